// Round 5
// baseline (496.016 us; speedup 1.0000x reference)
//
#include <hip/hip_runtime.h>

#define NN 50000
#define EE 400000
#define CC 128
#define TT 2

typedef float floatx4 __attribute__((ext_vector_type(4)));
typedef _Float16 half8 __attribute__((ext_vector_type(8)));
typedef _Float16 half2t __attribute__((ext_vector_type(2)));

__device__ __forceinline__ unsigned pk2h(float a, float b) {
    return __builtin_bit_cast(unsigned, __builtin_amdgcn_cvt_pkrtz(a, b));
}
// tanh-approx gelu (jax.nn.gelu default approximate=True), NaN-free form
__device__ __forceinline__ float gelu_f(float x) {
    float u = 0.7978845608028654f * (x + 0.044715f * x * x * x);
    float t = __expf(2.f * u);
    return x * (1.f - 1.f / (t + 1.f));
}
// f16x2 dot product accumulating f32: v_dot2_f32_f16 when available
__device__ __forceinline__ float dot2h(unsigned a, unsigned b, float c) {
#if __has_builtin(__builtin_amdgcn_fdot2)
    return __builtin_amdgcn_fdot2(__builtin_bit_cast(half2t, a),
                                  __builtin_bit_cast(half2t, b), c, false);
#else
    half2t av = __builtin_bit_cast(half2t, a), bv = __builtin_bit_cast(half2t, b);
    c = fmaf((float)av.x, (float)bv.x, c);
    return fmaf((float)av.y, (float)bv.y, c);
#endif
}

// ---- edge_index dtype probe: int64 arrays have zero high words ----
__global__ void k_detect(const int* __restrict__ ei, int* __restrict__ flag) {
    if (threadIdx.x == 0 && blockIdx.x == 0) {
        int orv = 0;
        for (int i = 1; i < 64; i += 2) orv |= ei[i];
        flag[0] = (orv == 0) ? 1 : 0;
    }
}

__global__ void k_count(const int* __restrict__ ei, const int* __restrict__ flag,
                        int* __restrict__ counts) {
    int i = blockIdx.x * 256 + threadIdx.x;
    if (i >= 2 * EE) return;
    int is64 = flag[0];
    int e = i / EE, j = i - e * EE;
    size_t pos = (size_t)(e * 2 + 1) * EE + j;
    int di = is64 ? ei[pos * 2] : ei[pos];
    di = min(max(di, 0), NN - 1);
    atomicAdd(&counts[e * NN + di], 1);
}

// ---- 3-phase scan: 49 blocks x 1024 elems per edge type ----
#define SCB ((NN + 1023) / 1024)
__global__ __launch_bounds__(256) void k_scan1(const int* __restrict__ counts,
                                               int* __restrict__ rowptr,
                                               int* __restrict__ bsum) {
    int e = blockIdx.y, b = blockIdx.x;
    int tid = threadIdx.x, lane = tid & 63, wid = tid >> 6;
    __shared__ int wsum[4];
    int base = b * 1024 + tid * 4;
    int v[4], s = 0;
#pragma unroll
    for (int k2 = 0; k2 < 4; k2++) {
        int i = base + k2;
        v[k2] = (i < NN) ? counts[e * NN + i] : 0;
        s += v[k2];
    }
    int incl = s;
#pragma unroll
    for (int off = 1; off < 64; off <<= 1) {
        int t2 = __shfl_up(incl, off);
        if (lane >= off) incl += t2;
    }
    if (lane == 63) wsum[wid] = incl;
    __syncthreads();
    int woff = 0;
    for (int w2 = 0; w2 < wid; w2++) woff += wsum[w2];
    int excl = woff + incl - s;
#pragma unroll
    for (int k2 = 0; k2 < 4; k2++) {
        int i = base + k2;
        if (i < NN) rowptr[e * (NN + 1) + i] = excl;
        excl += v[k2];
    }
    if (tid == 255) bsum[e * SCB + b] = woff + incl;
}

__global__ void k_scan2(int* __restrict__ bsum, int* __restrict__ rowptr) {
    int e = threadIdx.x >> 6, lane = threadIdx.x & 63;
    int v = (lane < SCB) ? bsum[e * SCB + lane] : 0;
    int incl = v;
#pragma unroll
    for (int off = 1; off < 64; off <<= 1) {
        int t2 = __shfl_up(incl, off);
        if (lane >= off) incl += t2;
    }
    if (lane < SCB) bsum[e * SCB + lane] = incl - v;
    if (lane == 63) rowptr[e * (NN + 1) + NN] = incl;
}

__global__ __launch_bounds__(256) void k_scan3(int* __restrict__ rowptr,
                                               const int* __restrict__ bsum,
                                               int* __restrict__ cursor) {
    int e = blockIdx.y, b = blockIdx.x;
    int off = bsum[e * SCB + b];
    int base = b * 1024 + threadIdx.x * 4;
#pragma unroll
    for (int k2 = 0; k2 < 4; k2++) {
        int i = base + k2;
        if (i < NN) {
            int r = rowptr[e * (NN + 1) + i] + off;
            rowptr[e * (NN + 1) + i] = r;
            cursor[e * NN + i] = r;
        }
    }
}

__global__ void k_scatter(const int* __restrict__ ei, const int* __restrict__ flag,
                          int* __restrict__ cursor, int* __restrict__ csr) {
    int i = blockIdx.x * 256 + threadIdx.x;
    if (i >= 2 * EE) return;
    int is64 = flag[0];
    int e = i / EE, j = i - e * EE;
    size_t ps = (size_t)(e * 2 + 0) * EE + j;
    size_t pd = (size_t)(e * 2 + 1) * EE + j;
    int si = is64 ? ei[ps * 2] : ei[ps];
    int di = is64 ? ei[pd * 2] : ei[pd];
    si = min(max(si, 0), NN - 1);
    di = min(max(di, 0), NN - 1);
    int pos = atomicAdd(&cursor[e * NN + di], 1);
    csr[(size_t)e * EE + pos] = si;
}

__global__ void k_cvt(const float4* __restrict__ x, uint2* __restrict__ xb) {
    int i = blockIdx.x * 256 + threadIdx.x;
    float4 v = x[i];
    uint2 o;
    o.x = pk2h(v.x, v.y);
    o.y = pk2h(v.z, v.w);
    xb[i] = o;
}

// Composed weights, both layers (l = blockIdx.y), A-frag row-major [m][k]:
//  W2[lt][n][k], n in [0,384): q*p_rel*scale | Wk∘a_rel | Wv∘m_rel ; k = input comp
__global__ void k_prep(const float* __restrict__ Wk, const float* __restrict__ Wq,
                       const float* __restrict__ Wv, const float* __restrict__ Wa,
                       const float* __restrict__ bk, const float* __restrict__ bq,
                       const float* __restrict__ bv,
                       const float* __restrict__ a_rel, const float* __restrict__ m_rel,
                       const float* __restrict__ p_rel,
                       _Float16* __restrict__ W2, _Float16* __restrict__ Wa2,
                       float* __restrict__ beff) {
    const float SCALE = 0.17677669529663687f;  // 1/sqrt(32)
    int l = blockIdx.y;
    int idx = blockIdx.x * 256 + threadIdx.x;
    if (idx < 2 * 384 * 128) {
        int t = idx / (384 * 128);
        int r = idx - t * 384 * 128;
        int n = r >> 7, k = r & 127;
        float val;
        if (n < 128) {
            val = Wq[((l * 2 + t) * 128 + k) * 128 + n] *
                  p_rel[(l * 2 + (1 - t)) * 4 + (n >> 5)] * SCALE;
        } else if (n < 256) {
            int nn = n - 128, h = nn >> 5, f = nn & 31;
            const float* wr = Wk + ((l * 2 + t) * 128 + k) * 128 + h * 32;
            const float* ar = a_rel + (((l * 2 + t) * 4 + h) * 32) * 32 + f;
            float s = 0.f;
            for (int d = 0; d < 32; d++) s += wr[d] * ar[d * 32];
            val = s;
        } else {
            int nn = n - 256, h = nn >> 5, f = nn & 31;
            const float* wr = Wv + ((l * 2 + t) * 128 + k) * 128 + h * 32;
            const float* mr = m_rel + (((l * 2 + t) * 4 + h) * 32) * 32 + f;
            float s = 0.f;
            for (int d = 0; d < 32; d++) s += wr[d] * mr[d * 32];
            val = s;
        }
        W2[((size_t)(l * 2 + t) * 384 + n) * 128 + k] = (_Float16)val;
    } else if (idx < 2 * 384 * 128 + 2 * 128 * 128) {
        int r = idx - 2 * 384 * 128;
        int t = r / (128 * 128);
        r -= t * 128 * 128;
        int n = r >> 7, k = r & 127;
        float val = Wa[((l * 2 + t) * 128 + k) * 128 + n];
        Wa2[((size_t)(l * 2 + t) * 128 + n) * 128 + k] = (_Float16)val;
    } else if (idx < 2 * 384 * 128 + 2 * 128 * 128 + 2 * 384) {
        int r = idx - (2 * 384 * 128 + 2 * 128 * 128);
        int t = r / 384, n = r - t * 384;
        float val;
        if (n < 128) {
            val = bq[(l * 2 + t) * 128 + n] * p_rel[(l * 2 + (1 - t)) * 4 + (n >> 5)] * SCALE;
        } else if (n < 256) {
            int nn = n - 128, h = nn >> 5, f = nn & 31;
            float s = 0.f;
            for (int d = 0; d < 32; d++)
                s += bk[(l * 2 + t) * 128 + h * 32 + d] *
                     a_rel[(((l * 2 + t) * 4 + h) * 32 + d) * 32 + f];
            val = s;
        } else {
            int nn = n - 256, h = nn >> 5, f = nn & 31;
            float s = 0.f;
            for (int d = 0; d < 32; d++)
                s += bv[(l * 2 + t) * 128 + h * 32 + d] *
                     m_rel[(((l * 2 + t) * 4 + h) * 32 + d) * 32 + f];
            val = s;
        }
        beff[(l * 2 + t) * 384 + n] = val;
    }
}

// Transposed GEMM: D[m=comp][n=node].  A = W2 (m in lanes.ln), B = x (node in lanes.ln).
// Lane holds comps quad*4+{0..3} of node ln -> packed 8B stores.
// Wave: 2 node-sets x NT*16 comps; block: 32 nodes x 384 comps (NT=6).
template <int NT>
__global__ __launch_bounds__(256) void k_gemm_qkv(const _Float16* __restrict__ xb,
                                                  const _Float16* __restrict__ W2,
                                                  const float* __restrict__ beff,
                                                  _Float16* __restrict__ qkv, int l,
                                                  int t0, int col0) {
    int t = t0 + blockIdx.y;
    int wid = threadIdx.x >> 6, lane = threadIdx.x & 63;
    int quad = lane >> 4, ln = lane & 15;
    int node0 = blockIdx.x * 32;
    const _Float16* Wt = W2 + (size_t)(l * 2 + t) * 384 * 128;
    half8 bf[2][4];
#pragma unroll
    for (int ns = 0; ns < 2; ns++) {
        int arow = min(node0 + ns * 16 + ln, NN - 1);
        const _Float16* xrow = xb + ((size_t)t * NN + arow) * CC;
#pragma unroll
        for (int kt = 0; kt < 4; kt++) bf[ns][kt] = *(const half8*)(xrow + kt * 32 + quad * 8);
    }
    floatx4 acc[NT][2];
#pragma unroll
    for (int nt = 0; nt < NT; nt++)
#pragma unroll
        for (int ns = 0; ns < 2; ns++) acc[nt][ns] = (floatx4){0.f, 0.f, 0.f, 0.f};
#pragma unroll
    for (int nt = 0; nt < NT; nt++) {
        int m = col0 + wid * NT * 16 + nt * 16 + ln;
#pragma unroll
        for (int kt = 0; kt < 4; kt++) {
            half8 af = *(const half8*)(Wt + (size_t)m * 128 + kt * 32 + quad * 8);
            acc[nt][0] = __builtin_amdgcn_mfma_f32_16x16x32_f16(af, bf[0][kt], acc[nt][0], 0, 0, 0);
            acc[nt][1] = __builtin_amdgcn_mfma_f32_16x16x32_f16(af, bf[1][kt], acc[nt][1], 0, 0, 0);
        }
    }
#pragma unroll
    for (int nt = 0; nt < NT; nt++) {
        int c0 = col0 + wid * NT * 16 + nt * 16 + quad * 4;
        float4 b4 = *(const float4*)(beff + (l * 2 + t) * 384 + c0);
#pragma unroll
        for (int ns = 0; ns < 2; ns++) {
            int node = node0 + ns * 16 + ln;
            if (node < NN) {
                uint2 o;
                o.x = pk2h(acc[nt][ns][0] + b4.x, acc[nt][ns][1] + b4.y);
                o.y = pk2h(acc[nt][ns][2] + b4.z, acc[nt][ns][3] + b4.w);
                *(uint2*)(qkv + ((size_t)t * NN + node) * 384 + c0) = o;
            }
        }
    }
}

// Dest-centric attention.  Wave = 1 dest node; 64 lanes = 4 edge slots x 16 segs.
// f16 tables: q.k via v_dot2_f32_f16 (packed, no unpack).  Writes RAW aggregate.
__global__ __launch_bounds__(256) void k_attn(const _Float16* __restrict__ qkv,
                                              const int* __restrict__ rowptr,
                                              const int* __restrict__ csr,
                                              _Float16* __restrict__ outg) {
    int t = blockIdx.y;
    int e = 1 - t;
    int st = 1 - t;
    int wid = threadIdx.x >> 6, lane = threadIdx.x & 63;
    int n = blockIdx.x * 4 + wid;
    int e4 = lane >> 4, s = lane & 15;
    const _Float16* qrow = qkv + ((size_t)t * NN + n) * 384;
    uint4 qd = *(const uint4*)(qrow + s * 8);
    int r0 = rowptr[e * (NN + 1) + n], r1 = rowptr[e * (NN + 1) + n + 1];
    r0 = __builtin_amdgcn_readfirstlane(r0);
    r1 = __builtin_amdgcn_readfirstlane(r1);
    const int* csrp = csr + (size_t)e * EE;
    const _Float16* sbase = qkv + (size_t)st * NN * 384;
    float acc[8] = {0.f, 0.f, 0.f, 0.f, 0.f, 0.f, 0.f, 0.f};
    float lsum = 0.f;

    auto load_chunk = [&](int jj, uint4& kd, uint4& vd, float& msk) {
        int idx = min(jj + e4, r1 - 1);
        int si = csrp[idx];
        const _Float16* row = sbase + (size_t)si * 384;
        kd = *(const uint4*)(row + 128 + s * 8);
        vd = *(const uint4*)(row + 256 + s * 8);
        msk = (jj + e4 < r1) ? 1.f : 0.f;
    };
    auto process = [&](const uint4& kd, const uint4& vd, float msk) {
        float p = 0.f;
        p = dot2h(kd.x, qd.x, p);
        p = dot2h(kd.y, qd.y, p);
        p = dot2h(kd.z, qd.z, p);
        p = dot2h(kd.w, qd.w, p);
        p += __shfl_xor(p, 1);
        p += __shfl_xor(p, 2);  // 4 segs of one head now hold the full head dot
        float w = __expf(p) * msk;
        lsum += w;
        half2t v0 = __builtin_bit_cast(half2t, vd.x), v1 = __builtin_bit_cast(half2t, vd.y);
        half2t v2 = __builtin_bit_cast(half2t, vd.z), v3 = __builtin_bit_cast(half2t, vd.w);
        acc[0] = fmaf(w, (float)v0.x, acc[0]);
        acc[1] = fmaf(w, (float)v0.y, acc[1]);
        acc[2] = fmaf(w, (float)v1.x, acc[2]);
        acc[3] = fmaf(w, (float)v1.y, acc[3]);
        acc[4] = fmaf(w, (float)v2.x, acc[4]);
        acc[5] = fmaf(w, (float)v2.y, acc[5]);
        acc[6] = fmaf(w, (float)v3.x, acc[6]);
        acc[7] = fmaf(w, (float)v3.y, acc[7]);
    };

    if (r0 < r1) {
        uint4 kdA, vdA;
        float mA;
        load_chunk(r0, kdA, vdA, mA);
        int j = r0;
        for (; j + 4 < r1; j += 4) {
            uint4 kdB, vdB;
            float mB;
            load_chunk(j + 4, kdB, vdB, mB);  // prefetch next chunk
            process(kdA, vdA, mA);
            kdA = kdB; vdA = vdB; mA = mB;
        }
        process(kdA, vdA, mA);
    }
#pragma unroll
    for (int i = 0; i < 8; i++) {
        acc[i] += __shfl_xor(acc[i], 16);
        acc[i] += __shfl_xor(acc[i], 32);
    }
    lsum += __shfl_xor(lsum, 16);
    lsum += __shfl_xor(lsum, 32);
    float inv = 1.f / (lsum + 1e-16f);
    if (e4 == 0) {
        uint4 o;
        o.x = pk2h(acc[0] * inv, acc[1] * inv);
        o.y = pk2h(acc[2] * inv, acc[3] * inv);
        o.z = pk2h(acc[4] * inv, acc[5] * inv);
        o.w = pk2h(acc[6] * inv, acc[7] * inv);
        *(uint4*)(outg + ((size_t)t * NN + n) * CC + s * 8) = o;
    }
}

// Transposed epilogue: o = gelu(outg) @ Wa + ba ; skip-blend ; LayerNorm ; ReLU.
// Wave: 16 nodes x 128 comps; lane holds comps {nt*16+quad*4+reg} of node ln.
// LN: in-lane 32-sum + 2 quad shuffles.  Stores: 8B f16 packs or float4.
__global__ __launch_bounds__(256) void k_epilogue(
    const _Float16* __restrict__ outg, const _Float16* __restrict__ Wa2,
    const float* __restrict__ ba, const float* __restrict__ skipv,
    const float* __restrict__ ln_g, const float* __restrict__ ln_b,
    const _Float16* __restrict__ xb_cur, _Float16* __restrict__ xb_next,
    float* __restrict__ xout, int l) {
    int t = blockIdx.y;
    int wid = threadIdx.x >> 6, lane = threadIdx.x & 63;
    int quad = lane >> 4, ln = lane & 15;
    int node0 = blockIdx.x * 64 + wid * 16;
    int node = node0 + ln;
    int arow = min(node, NN - 1);
    const _Float16* grow = outg + ((size_t)t * NN + arow) * CC;
    half8 bf[4];
#pragma unroll
    for (int kt = 0; kt < 4; kt++) {
        uint4 gd = *(const uint4*)(grow + kt * 32 + quad * 8);
        half2t h0 = __builtin_bit_cast(half2t, gd.x), h1 = __builtin_bit_cast(half2t, gd.y);
        half2t h2 = __builtin_bit_cast(half2t, gd.z), h3 = __builtin_bit_cast(half2t, gd.w);
        uint4 pk;
        pk.x = pk2h(gelu_f((float)h0.x), gelu_f((float)h0.y));
        pk.y = pk2h(gelu_f((float)h1.x), gelu_f((float)h1.y));
        pk.z = pk2h(gelu_f((float)h2.x), gelu_f((float)h2.y));
        pk.w = pk2h(gelu_f((float)h3.x), gelu_f((float)h3.y));
        bf[kt] = __builtin_bit_cast(half8, pk);
    }
    const _Float16* Wt = Wa2 + (size_t)(l * 2 + t) * 128 * 128;
    floatx4 acc[8];
#pragma unroll
    for (int nt = 0; nt < 8; nt++) acc[nt] = (floatx4){0.f, 0.f, 0.f, 0.f};
#pragma unroll
    for (int nt = 0; nt < 8; nt++) {
        int m = nt * 16 + ln;
#pragma unroll
        for (int kt = 0; kt < 4; kt++) {
            half8 af = *(const half8*)(Wt + (size_t)m * 128 + kt * 32 + quad * 8);
            acc[nt] = __builtin_amdgcn_mfma_f32_16x16x32_f16(af, bf[kt], acc[nt], 0, 0, 0);
        }
    }
    float sv = skipv[l * TT + t];
    float beta = 1.f / (1.f + __expf(-sv));
    const _Float16* xrow = xb_cur + ((size_t)t * NN + arow) * CC;
    float xn[8][4];
    float s1 = 0.f, s2 = 0.f;
#pragma unroll
    for (int nt = 0; nt < 8; nt++) {
        int c0 = nt * 16 + quad * 4;
        float4 b4 = *(const float4*)(ba + (l * TT + t) * CC + c0);
        uint2 xw = *(const uint2*)(xrow + c0);
        half2t x0 = __builtin_bit_cast(half2t, xw.x), x1 = __builtin_bit_cast(half2t, xw.y);
        float xv[4] = {(float)x0.x, (float)x0.y, (float)x1.x, (float)x1.y};
        float bb[4] = {b4.x, b4.y, b4.z, b4.w};
#pragma unroll
        for (int reg = 0; reg < 4; reg++) {
            float o = acc[nt][reg] + bb[reg];
            float v = beta * o + (1.f - beta) * xv[reg];
            xn[nt][reg] = v;
            s1 += v;
            s2 += v * v;
        }
    }
    s1 += __shfl_xor(s1, 16); s1 += __shfl_xor(s1, 32);
    s2 += __shfl_xor(s2, 16); s2 += __shfl_xor(s2, 32);
    float mu = s1 * (1.f / CC);
    float var = s2 * (1.f / CC) - mu * mu;
    float rs = rsqrtf(var + 1e-5f);
    if (node < NN) {
#pragma unroll
        for (int nt = 0; nt < 8; nt++) {
            int c0 = nt * 16 + quad * 4;
            float4 g4 = *(const float4*)(ln_g + (l * TT + t) * CC + c0);
            float4 be4 = *(const float4*)(ln_b + (l * TT + t) * CC + c0);
            float y0 = fmaxf((xn[nt][0] - mu) * rs * g4.x + be4.x, 0.f);
            float y1 = fmaxf((xn[nt][1] - mu) * rs * g4.y + be4.y, 0.f);
            float y2 = fmaxf((xn[nt][2] - mu) * rs * g4.z + be4.z, 0.f);
            float y3 = fmaxf((xn[nt][3] - mu) * rs * g4.w + be4.w, 0.f);
            if (xout) {
                float4 o4 = {y0, y1, y2, y3};
                *(float4*)(xout + (size_t)node * CC + c0) = o4;
            } else {
                uint2 o;
                o.x = pk2h(y0, y1);
                o.y = pk2h(y2, y3);
                *(uint2*)(xb_next + ((size_t)t * NN + node) * CC + c0) = o;
            }
        }
    }
}

extern "C" void kernel_launch(void* const* d_in, const int* in_sizes, int n_in,
                              void* d_out, int out_size, void* d_ws, size_t ws_size,
                              hipStream_t stream) {
    const float* x = (const float*)d_in[0];
    const int* ei = (const int*)d_in[1];
    const float* Wk = (const float*)d_in[2];
    const float* bk = (const float*)d_in[3];
    const float* Wq = (const float*)d_in[4];
    const float* bq = (const float*)d_in[5];
    const float* Wv = (const float*)d_in[6];
    const float* bv = (const float*)d_in[7];
    const float* Wa = (const float*)d_in[8];
    const float* ba = (const float*)d_in[9];
    const float* skip = (const float*)d_in[10];
    const float* a_rel = (const float*)d_in[11];
    const float* m_rel = (const float*)d_in[12];
    const float* p_rel = (const float*)d_in[13];
    const float* ln_g = (const float*)d_in[14];
    const float* ln_b = (const float*)d_in[15];

    char* ws = (char*)d_ws;
    size_t off = 0;
    auto alloc = [&](size_t b) {
        size_t o = off;
        off = (off + b + 255) & ~(size_t)255;
        return o;
    };
    _Float16* xbA = (_Float16*)(ws + alloc((size_t)TT * NN * CC * 2));
    _Float16* xbB = (_Float16*)(ws + alloc((size_t)TT * NN * CC * 2));
    _Float16* qkv = (_Float16*)(ws + alloc((size_t)TT * NN * 384 * 2));
    _Float16* outg = (_Float16*)(ws + alloc((size_t)TT * NN * CC * 2));
    _Float16* W2 = (_Float16*)(ws + alloc((size_t)2 * TT * 384 * 128 * 2));
    _Float16* Wa2 = (_Float16*)(ws + alloc((size_t)2 * TT * 128 * 128 * 2));
    float* beff = (float*)(ws + alloc((size_t)2 * TT * 384 * 4));
    int* counts = (int*)(ws + alloc((size_t)2 * NN * 4));
    int* cursor = (int*)(ws + alloc((size_t)2 * NN * 4));
    int* rowptr = (int*)(ws + alloc((size_t)2 * (NN + 1) * 4));
    int* csr = (int*)(ws + alloc((size_t)2 * EE * 4));
    int* flag = (int*)(ws + alloc(256));
    int* bsum = (int*)(ws + alloc((size_t)2 * SCB * 4 + 256));
    (void)ws_size; (void)in_sizes; (void)n_in; (void)out_size;

    k_detect<<<1, 64, 0, stream>>>(ei, flag);
    (void)hipMemsetAsync(counts, 0, (size_t)2 * NN * 4, stream);
    k_count<<<(2 * EE + 255) / 256, 256, 0, stream>>>(ei, flag, counts);
    k_scan1<<<dim3(SCB, 2), 256, 0, stream>>>(counts, rowptr, bsum);
    k_scan2<<<1, 128, 0, stream>>>(bsum, rowptr);
    k_scan3<<<dim3(SCB, 2), 256, 0, stream>>>(rowptr, bsum, cursor);
    k_scatter<<<(2 * EE + 255) / 256, 256, 0, stream>>>(ei, flag, cursor, csr);
    k_cvt<<<(TT * NN * CC / 4 + 255) / 256, 256, 0, stream>>>((const float4*)x, (uint2*)xbA);
    k_prep<<<dim3((2 * 384 * 128 + 2 * 128 * 128 + 2 * 384 + 255) / 256, 2), 256, 0, stream>>>(
        Wk, Wq, Wv, Wa, bk, bq, bv, a_rel, m_rel, p_rel, W2, Wa2, beff);

    const int GB = (NN + 31) / 32;
    // layer 0: full qkv for both types
    k_gemm_qkv<6><<<dim3(GB, 2), 256, 0, stream>>>(xbA, W2, beff, qkv, 0, 0, 0);
    k_attn<<<dim3(NN / 4, 2), 256, 0, stream>>>(qkv, rowptr, csr, outg);
    k_epilogue<<<dim3((NN + 63) / 64, 2), 256, 0, stream>>>(
        outg, Wa2, ba, skip, ln_g, ln_b, xbA, xbB, nullptr, 0);
    // layer 1: only t0 output needed -> t0 needs q cols [0,128), t1 needs k/v cols [128,384)
    k_gemm_qkv<2><<<dim3(GB, 1), 256, 0, stream>>>(xbB, W2, beff, qkv, 1, 0, 0);
    k_gemm_qkv<4><<<dim3(GB, 1), 256, 0, stream>>>(xbB, W2, beff, qkv, 1, 1, 128);
    k_attn<<<dim3(NN / 4, 1), 256, 0, stream>>>(qkv, rowptr, csr, outg);
    k_epilogue<<<dim3((NN + 63) / 64, 1), 256, 0, stream>>>(
        outg, Wa2, ba, skip, ln_g, ln_b, xbB, nullptr, (float*)d_out, 1);
}

// Round 6
// 474.606 us; speedup vs baseline: 1.0451x; 1.0451x over previous
//
#include <hip/hip_runtime.h>

#define NN 50000
#define EE 400000
#define CC 128
#define TT 2

typedef float floatx4 __attribute__((ext_vector_type(4)));
typedef _Float16 half8 __attribute__((ext_vector_type(8)));
typedef _Float16 half2t __attribute__((ext_vector_type(2)));

__device__ __forceinline__ unsigned pk2h(float a, float b) {
    return __builtin_bit_cast(unsigned, __builtin_amdgcn_cvt_pkrtz(a, b));
}
// tanh-approx gelu (jax.nn.gelu default approximate=True), NaN-free form
__device__ __forceinline__ float gelu_f(float x) {
    float u = 0.7978845608028654f * (x + 0.044715f * x * x * x);
    float t = __expf(2.f * u);
    return x * (1.f - 1.f / (t + 1.f));
}
// f16x2 dot product accumulating f32: v_dot2_f32_f16 when available
__device__ __forceinline__ float dot2h(unsigned a, unsigned b, float c) {
#if __has_builtin(__builtin_amdgcn_fdot2)
    return __builtin_amdgcn_fdot2(__builtin_bit_cast(half2t, a),
                                  __builtin_bit_cast(half2t, b), c, false);
#else
    half2t av = __builtin_bit_cast(half2t, a), bv = __builtin_bit_cast(half2t, b);
    c = fmaf((float)av.x, (float)bv.x, c);
    return fmaf((float)av.y, (float)bv.y, c);
#endif
}

// ---- edge_index dtype probe: int64 arrays have zero high words ----
__global__ void k_detect(const int* __restrict__ ei, int* __restrict__ flag) {
    if (threadIdx.x == 0 && blockIdx.x == 0) {
        int orv = 0;
        for (int i = 1; i < 64; i += 2) orv |= ei[i];
        flag[0] = (orv == 0) ? 1 : 0;
    }
}

__global__ void k_count(const int* __restrict__ ei, const int* __restrict__ flag,
                        int* __restrict__ counts) {
    int i = blockIdx.x * 256 + threadIdx.x;
    if (i >= 2 * EE) return;
    int is64 = flag[0];
    int e = i / EE, j = i - e * EE;
    size_t pos = (size_t)(e * 2 + 1) * EE + j;
    int di = is64 ? ei[pos * 2] : ei[pos];
    di = min(max(di, 0), NN - 1);
    atomicAdd(&counts[e * NN + di], 1);
}

// ---- 3-phase scan: 49 blocks x 1024 elems per edge type ----
#define SCB ((NN + 1023) / 1024)
__global__ __launch_bounds__(256) void k_scan1(const int* __restrict__ counts,
                                               int* __restrict__ rowptr,
                                               int* __restrict__ bsum) {
    int e = blockIdx.y, b = blockIdx.x;
    int tid = threadIdx.x, lane = tid & 63, wid = tid >> 6;
    __shared__ int wsum[4];
    int base = b * 1024 + tid * 4;
    int v[4], s = 0;
#pragma unroll
    for (int k2 = 0; k2 < 4; k2++) {
        int i = base + k2;
        v[k2] = (i < NN) ? counts[e * NN + i] : 0;
        s += v[k2];
    }
    int incl = s;
#pragma unroll
    for (int off = 1; off < 64; off <<= 1) {
        int t2 = __shfl_up(incl, off);
        if (lane >= off) incl += t2;
    }
    if (lane == 63) wsum[wid] = incl;
    __syncthreads();
    int woff = 0;
    for (int w2 = 0; w2 < wid; w2++) woff += wsum[w2];
    int excl = woff + incl - s;
#pragma unroll
    for (int k2 = 0; k2 < 4; k2++) {
        int i = base + k2;
        if (i < NN) rowptr[e * (NN + 1) + i] = excl;
        excl += v[k2];
    }
    if (tid == 255) bsum[e * SCB + b] = woff + incl;
}

__global__ void k_scan2(int* __restrict__ bsum, int* __restrict__ rowptr) {
    int e = threadIdx.x >> 6, lane = threadIdx.x & 63;
    int v = (lane < SCB) ? bsum[e * SCB + lane] : 0;
    int incl = v;
#pragma unroll
    for (int off = 1; off < 64; off <<= 1) {
        int t2 = __shfl_up(incl, off);
        if (lane >= off) incl += t2;
    }
    if (lane < SCB) bsum[e * SCB + lane] = incl - v;
    if (lane == 63) rowptr[e * (NN + 1) + NN] = incl;
}

__global__ __launch_bounds__(256) void k_scan3(int* __restrict__ rowptr,
                                               const int* __restrict__ bsum,
                                               int* __restrict__ cursor) {
    int e = blockIdx.y, b = blockIdx.x;
    int off = bsum[e * SCB + b];
    int base = b * 1024 + threadIdx.x * 4;
#pragma unroll
    for (int k2 = 0; k2 < 4; k2++) {
        int i = base + k2;
        if (i < NN) {
            int r = rowptr[e * (NN + 1) + i] + off;
            rowptr[e * (NN + 1) + i] = r;
            cursor[e * NN + i] = r;
        }
    }
}

__global__ void k_scatter(const int* __restrict__ ei, const int* __restrict__ flag,
                          int* __restrict__ cursor, int* __restrict__ csr) {
    int i = blockIdx.x * 256 + threadIdx.x;
    if (i >= 2 * EE) return;
    int is64 = flag[0];
    int e = i / EE, j = i - e * EE;
    size_t ps = (size_t)(e * 2 + 0) * EE + j;
    size_t pd = (size_t)(e * 2 + 1) * EE + j;
    int si = is64 ? ei[ps * 2] : ei[ps];
    int di = is64 ? ei[pd * 2] : ei[pd];
    si = min(max(si, 0), NN - 1);
    di = min(max(di, 0), NN - 1);
    int pos = atomicAdd(&cursor[e * NN + di], 1);
    csr[(size_t)e * EE + pos] = si;
}

__global__ void k_cvt(const float4* __restrict__ x, uint2* __restrict__ xb) {
    int i = blockIdx.x * 256 + threadIdx.x;
    float4 v = x[i];
    uint2 o;
    o.x = pk2h(v.x, v.y);
    o.y = pk2h(v.z, v.w);
    xb[i] = o;
}

// Composed weights, both layers (l = blockIdx.y), A-frag row-major [m][k]:
//  W2[lt][n][k], n in [0,384): q*p_rel*scale | Wk∘a_rel | Wv∘m_rel ; k = input comp
__global__ void k_prep(const float* __restrict__ Wk, const float* __restrict__ Wq,
                       const float* __restrict__ Wv, const float* __restrict__ Wa,
                       const float* __restrict__ bk, const float* __restrict__ bq,
                       const float* __restrict__ bv,
                       const float* __restrict__ a_rel, const float* __restrict__ m_rel,
                       const float* __restrict__ p_rel,
                       _Float16* __restrict__ W2, _Float16* __restrict__ Wa2,
                       float* __restrict__ beff) {
    const float SCALE = 0.17677669529663687f;  // 1/sqrt(32)
    int l = blockIdx.y;
    int idx = blockIdx.x * 256 + threadIdx.x;
    if (idx < 2 * 384 * 128) {
        int t = idx / (384 * 128);
        int r = idx - t * 384 * 128;
        int n = r >> 7, k = r & 127;
        float val;
        if (n < 128) {
            val = Wq[((l * 2 + t) * 128 + k) * 128 + n] *
                  p_rel[(l * 2 + (1 - t)) * 4 + (n >> 5)] * SCALE;
        } else if (n < 256) {
            int nn = n - 128, h = nn >> 5, f = nn & 31;
            const float* wr = Wk + ((l * 2 + t) * 128 + k) * 128 + h * 32;
            const float* ar = a_rel + (((l * 2 + t) * 4 + h) * 32) * 32 + f;
            float s = 0.f;
            for (int d = 0; d < 32; d++) s += wr[d] * ar[d * 32];
            val = s;
        } else {
            int nn = n - 256, h = nn >> 5, f = nn & 31;
            const float* wr = Wv + ((l * 2 + t) * 128 + k) * 128 + h * 32;
            const float* mr = m_rel + (((l * 2 + t) * 4 + h) * 32) * 32 + f;
            float s = 0.f;
            for (int d = 0; d < 32; d++) s += wr[d] * mr[d * 32];
            val = s;
        }
        W2[((size_t)(l * 2 + t) * 384 + n) * 128 + k] = (_Float16)val;
    } else if (idx < 2 * 384 * 128 + 2 * 128 * 128) {
        int r = idx - 2 * 384 * 128;
        int t = r / (128 * 128);
        r -= t * 128 * 128;
        int n = r >> 7, k = r & 127;
        float val = Wa[((l * 2 + t) * 128 + k) * 128 + n];
        Wa2[((size_t)(l * 2 + t) * 128 + n) * 128 + k] = (_Float16)val;
    } else if (idx < 2 * 384 * 128 + 2 * 128 * 128 + 2 * 384) {
        int r = idx - (2 * 384 * 128 + 2 * 128 * 128);
        int t = r / 384, n = r - t * 384;
        float val;
        if (n < 128) {
            val = bq[(l * 2 + t) * 128 + n] * p_rel[(l * 2 + (1 - t)) * 4 + (n >> 5)] * SCALE;
        } else if (n < 256) {
            int nn = n - 128, h = nn >> 5, f = nn & 31;
            float s = 0.f;
            for (int d = 0; d < 32; d++)
                s += bk[(l * 2 + t) * 128 + h * 32 + d] *
                     a_rel[(((l * 2 + t) * 4 + h) * 32 + d) * 32 + f];
            val = s;
        } else {
            int nn = n - 256, h = nn >> 5, f = nn & 31;
            float s = 0.f;
            for (int d = 0; d < 32; d++)
                s += bv[(l * 2 + t) * 128 + h * 32 + d] *
                     m_rel[(((l * 2 + t) * 4 + h) * 32 + d) * 32 + f];
            val = s;
        }
        beff[(l * 2 + t) * 384 + n] = val;
    }
}

// Transposed GEMM + LDS-staged coalesced stores.
// D[m=comp][n=node]; lane holds comps quad*4+{0..3} of node ln.
// Tile 32 nodes x NT*64 comps staged in LDS, flat copy-out in full cache lines.
template <int NT>
__global__ __launch_bounds__(256) void k_gemm_qkv(const _Float16* __restrict__ xb,
                                                  const _Float16* __restrict__ W2,
                                                  const float* __restrict__ beff,
                                                  _Float16* __restrict__ qkv, int l,
                                                  int t0, int col0) {
    constexpr int RW = NT * 64;       // tile row width (halfs)
    constexpr int ROWH = RW + 4;      // +8B pad: bank-stagger
    __shared__ _Float16 tile[32 * ROWH];
    int t = t0 + blockIdx.y;
    int tid = threadIdx.x;
    int wid = tid >> 6, lane = tid & 63;
    int quad = lane >> 4, ln = lane & 15;
    int node0 = blockIdx.x * 32;
    const _Float16* Wt = W2 + (size_t)(l * 2 + t) * 384 * 128;
    half8 bf[2][4];
#pragma unroll
    for (int ns = 0; ns < 2; ns++) {
        int arow = min(node0 + ns * 16 + ln, NN - 1);
        const _Float16* xrow = xb + ((size_t)t * NN + arow) * CC;
#pragma unroll
        for (int kt = 0; kt < 4; kt++) bf[ns][kt] = *(const half8*)(xrow + kt * 32 + quad * 8);
    }
    floatx4 acc[NT][2];
#pragma unroll
    for (int nt = 0; nt < NT; nt++)
#pragma unroll
        for (int ns = 0; ns < 2; ns++) acc[nt][ns] = (floatx4){0.f, 0.f, 0.f, 0.f};
#pragma unroll
    for (int nt = 0; nt < NT; nt++) {
        int m = col0 + wid * NT * 16 + nt * 16 + ln;
#pragma unroll
        for (int kt = 0; kt < 4; kt++) {
            half8 af = *(const half8*)(Wt + (size_t)m * 128 + kt * 32 + quad * 8);
            acc[nt][0] = __builtin_amdgcn_mfma_f32_16x16x32_f16(af, bf[0][kt], acc[nt][0], 0, 0, 0);
            acc[nt][1] = __builtin_amdgcn_mfma_f32_16x16x32_f16(af, bf[1][kt], acc[nt][1], 0, 0, 0);
        }
    }
    // stage to LDS (+bias), lane -> (node=ln, 4 comps)
#pragma unroll
    for (int nt = 0; nt < NT; nt++) {
        int lc0 = wid * NT * 16 + nt * 16 + quad * 4;
        float4 b4 = *(const float4*)(beff + (l * 2 + t) * 384 + col0 + lc0);
#pragma unroll
        for (int ns = 0; ns < 2; ns++) {
            int nl = ns * 16 + ln;
            uint2 o;
            o.x = pk2h(acc[nt][ns][0] + b4.x, acc[nt][ns][1] + b4.y);
            o.y = pk2h(acc[nt][ns][2] + b4.z, acc[nt][ns][3] + b4.w);
            *(uint2*)(tile + nl * ROWH + lc0) = o;
        }
    }
    __syncthreads();
    // coalesced copy-out: NT*256 chunks of 16 B, contiguous per node row
    constexpr int CPR = NT * 8;  // 16B chunks per row
#pragma unroll
    for (int p = 0; p < NT; p++) {
        int c = p * 256 + tid;
        int row = c / CPR, ch = c - row * CPR;
        int node = node0 + row;
        if (node < NN)
            *(uint4*)(qkv + ((size_t)t * NN + node) * 384 + col0 + ch * 8) =
                *(const uint4*)(tile + row * ROWH + ch * 8);
    }
}

// Dest-centric attention.  Wave = 1 dest node; 64 lanes = 4 edge slots x 16 segs.
// f16 tables: q.k via v_dot2_f32_f16 (packed, no unpack).  Writes RAW aggregate.
__global__ __launch_bounds__(256) void k_attn(const _Float16* __restrict__ qkv,
                                              const int* __restrict__ rowptr,
                                              const int* __restrict__ csr,
                                              _Float16* __restrict__ outg) {
    int t = blockIdx.y;
    int e = 1 - t;
    int st = 1 - t;
    int wid = threadIdx.x >> 6, lane = threadIdx.x & 63;
    int n = blockIdx.x * 4 + wid;
    int e4 = lane >> 4, s = lane & 15;
    const _Float16* qrow = qkv + ((size_t)t * NN + n) * 384;
    uint4 qd = *(const uint4*)(qrow + s * 8);
    int r0 = rowptr[e * (NN + 1) + n], r1 = rowptr[e * (NN + 1) + n + 1];
    r0 = __builtin_amdgcn_readfirstlane(r0);
    r1 = __builtin_amdgcn_readfirstlane(r1);
    const int* csrp = csr + (size_t)e * EE;
    const _Float16* sbase = qkv + (size_t)st * NN * 384;
    float acc[8] = {0.f, 0.f, 0.f, 0.f, 0.f, 0.f, 0.f, 0.f};
    float lsum = 0.f;

    auto load_chunk = [&](int jj, uint4& kd, uint4& vd, float& msk) {
        int idx = min(jj + e4, r1 - 1);
        int si = csrp[idx];
        const _Float16* row = sbase + (size_t)si * 384;
        kd = *(const uint4*)(row + 128 + s * 8);
        vd = *(const uint4*)(row + 256 + s * 8);
        msk = (jj + e4 < r1) ? 1.f : 0.f;
    };
    auto process = [&](const uint4& kd, const uint4& vd, float msk) {
        float p = 0.f;
        p = dot2h(kd.x, qd.x, p);
        p = dot2h(kd.y, qd.y, p);
        p = dot2h(kd.z, qd.z, p);
        p = dot2h(kd.w, qd.w, p);
        p += __shfl_xor(p, 1);
        p += __shfl_xor(p, 2);  // 4 segs of one head now hold the full head dot
        float w = __expf(p) * msk;
        lsum += w;
        half2t v0 = __builtin_bit_cast(half2t, vd.x), v1 = __builtin_bit_cast(half2t, vd.y);
        half2t v2 = __builtin_bit_cast(half2t, vd.z), v3 = __builtin_bit_cast(half2t, vd.w);
        acc[0] = fmaf(w, (float)v0.x, acc[0]);
        acc[1] = fmaf(w, (float)v0.y, acc[1]);
        acc[2] = fmaf(w, (float)v1.x, acc[2]);
        acc[3] = fmaf(w, (float)v1.y, acc[3]);
        acc[4] = fmaf(w, (float)v2.x, acc[4]);
        acc[5] = fmaf(w, (float)v2.y, acc[5]);
        acc[6] = fmaf(w, (float)v3.x, acc[6]);
        acc[7] = fmaf(w, (float)v3.y, acc[7]);
    };

    if (r0 < r1) {
        uint4 kdA, vdA;
        float mA;
        load_chunk(r0, kdA, vdA, mA);
        int j = r0;
        for (; j + 4 < r1; j += 4) {
            uint4 kdB, vdB;
            float mB;
            load_chunk(j + 4, kdB, vdB, mB);  // prefetch next chunk
            process(kdA, vdA, mA);
            kdA = kdB; vdA = vdB; mA = mB;
        }
        process(kdA, vdA, mA);
    }
#pragma unroll
    for (int i = 0; i < 8; i++) {
        acc[i] += __shfl_xor(acc[i], 16);
        acc[i] += __shfl_xor(acc[i], 32);
    }
    lsum += __shfl_xor(lsum, 16);
    lsum += __shfl_xor(lsum, 32);
    float inv = 1.f / (lsum + 1e-16f);
    if (e4 == 0) {
        uint4 o;
        o.x = pk2h(acc[0] * inv, acc[1] * inv);
        o.y = pk2h(acc[2] * inv, acc[3] * inv);
        o.z = pk2h(acc[4] * inv, acc[5] * inv);
        o.w = pk2h(acc[6] * inv, acc[7] * inv);
        *(uint4*)(outg + ((size_t)t * NN + n) * CC + s * 8) = o;
    }
}

// Transposed epilogue with LDS-staged coalesced stores.
// o = gelu(outg) @ Wa + ba ; skip-blend ; LayerNorm ; ReLU.
// Tile 64 nodes x 128 comps; f16 path 17KB, f32 path 33KB LDS.
__global__ __launch_bounds__(256) void k_epilogue(
    const _Float16* __restrict__ outg, const _Float16* __restrict__ Wa2,
    const float* __restrict__ ba, const float* __restrict__ skipv,
    const float* __restrict__ ln_g, const float* __restrict__ ln_b,
    const _Float16* __restrict__ xb_cur, _Float16* __restrict__ xb_next,
    float* __restrict__ xout, int l) {
    __shared__ float smem[64 * 130];  // f32 view: row stride 130; f16 view: stride 132
    _Float16* smem_h = (_Float16*)smem;
    int t = blockIdx.y;
    int tid = threadIdx.x;
    int wid = tid >> 6, lane = tid & 63;
    int quad = lane >> 4, ln = lane & 15;
    int node0 = blockIdx.x * 64;
    int nloc = wid * 16 + ln;
    int node = node0 + nloc;
    int arow = min(node, NN - 1);
    const _Float16* grow = outg + ((size_t)t * NN + arow) * CC;
    half8 bf[4];
#pragma unroll
    for (int kt = 0; kt < 4; kt++) {
        uint4 gd = *(const uint4*)(grow + kt * 32 + quad * 8);
        half2t h0 = __builtin_bit_cast(half2t, gd.x), h1 = __builtin_bit_cast(half2t, gd.y);
        half2t h2 = __builtin_bit_cast(half2t, gd.z), h3 = __builtin_bit_cast(half2t, gd.w);
        uint4 pk;
        pk.x = pk2h(gelu_f((float)h0.x), gelu_f((float)h0.y));
        pk.y = pk2h(gelu_f((float)h1.x), gelu_f((float)h1.y));
        pk.z = pk2h(gelu_f((float)h2.x), gelu_f((float)h2.y));
        pk.w = pk2h(gelu_f((float)h3.x), gelu_f((float)h3.y));
        bf[kt] = __builtin_bit_cast(half8, pk);
    }
    const _Float16* Wt = Wa2 + (size_t)(l * 2 + t) * 128 * 128;
    floatx4 acc[8];
#pragma unroll
    for (int nt = 0; nt < 8; nt++) acc[nt] = (floatx4){0.f, 0.f, 0.f, 0.f};
#pragma unroll
    for (int nt = 0; nt < 8; nt++) {
        int m = nt * 16 + ln;
#pragma unroll
        for (int kt = 0; kt < 4; kt++) {
            half8 af = *(const half8*)(Wt + (size_t)m * 128 + kt * 32 + quad * 8);
            acc[nt] = __builtin_amdgcn_mfma_f32_16x16x32_f16(af, bf[kt], acc[nt], 0, 0, 0);
        }
    }
    float sv = skipv[l * TT + t];
    float beta = 1.f / (1.f + __expf(-sv));
    const _Float16* xrow = xb_cur + ((size_t)t * NN + arow) * CC;
    float xn[8][4];
    float s1 = 0.f, s2 = 0.f;
#pragma unroll
    for (int nt = 0; nt < 8; nt++) {
        int c0 = nt * 16 + quad * 4;
        float4 b4 = *(const float4*)(ba + (l * TT + t) * CC + c0);
        uint2 xw = *(const uint2*)(xrow + c0);
        half2t x0 = __builtin_bit_cast(half2t, xw.x), x1 = __builtin_bit_cast(half2t, xw.y);
        float xv[4] = {(float)x0.x, (float)x0.y, (float)x1.x, (float)x1.y};
        float bb[4] = {b4.x, b4.y, b4.z, b4.w};
#pragma unroll
        for (int reg = 0; reg < 4; reg++) {
            float o = acc[nt][reg] + bb[reg];
            float v = beta * o + (1.f - beta) * xv[reg];
            xn[nt][reg] = v;
            s1 += v;
            s2 += v * v;
        }
    }
    s1 += __shfl_xor(s1, 16); s1 += __shfl_xor(s1, 32);
    s2 += __shfl_xor(s2, 16); s2 += __shfl_xor(s2, 32);
    float mu = s1 * (1.f / CC);
    float var = s2 * (1.f / CC) - mu * mu;
    float rs = rsqrtf(var + 1e-5f);
#pragma unroll
    for (int nt = 0; nt < 8; nt++) {
        int c0 = nt * 16 + quad * 4;
        float4 g4 = *(const float4*)(ln_g + (l * TT + t) * CC + c0);
        float4 be4 = *(const float4*)(ln_b + (l * TT + t) * CC + c0);
        float y0 = fmaxf((xn[nt][0] - mu) * rs * g4.x + be4.x, 0.f);
        float y1 = fmaxf((xn[nt][1] - mu) * rs * g4.y + be4.y, 0.f);
        float y2 = fmaxf((xn[nt][2] - mu) * rs * g4.z + be4.z, 0.f);
        float y3 = fmaxf((xn[nt][3] - mu) * rs * g4.w + be4.w, 0.f);
        if (xout) {
            float4 o4 = {y0, y1, y2, y3};
            *(float4*)(smem + nloc * 130 + c0) = o4;
        } else {
            uint2 o;
            o.x = pk2h(y0, y1);
            o.y = pk2h(y2, y3);
            *(uint2*)(smem_h + nloc * 132 + c0) = o;
        }
    }
    __syncthreads();
    if (xout) {
        // 64 rows x 512 B = 32 chunks/row of 16 B; 2048 chunks, 8 passes
#pragma unroll
        for (int p = 0; p < 8; p++) {
            int c = p * 256 + tid;
            int row = c >> 5, ch = c & 31;
            int nd = node0 + row;
            if (nd < NN)
                *(uint4*)(xout + (size_t)nd * CC + ch * 4) =
                    *(const uint4*)(smem + row * 130 + ch * 4);
        }
    } else {
        // 64 rows x 256 B = 16 chunks/row of 16 B; 1024 chunks, 4 passes
#pragma unroll
        for (int p = 0; p < 4; p++) {
            int c = p * 256 + tid;
            int row = c >> 4, ch = c & 15;
            int nd = node0 + row;
            if (nd < NN)
                *(uint4*)(xb_next + ((size_t)t * NN + nd) * CC + ch * 8) =
                    *(const uint4*)(smem_h + row * 132 + ch * 8);
        }
    }
}

extern "C" void kernel_launch(void* const* d_in, const int* in_sizes, int n_in,
                              void* d_out, int out_size, void* d_ws, size_t ws_size,
                              hipStream_t stream) {
    const float* x = (const float*)d_in[0];
    const int* ei = (const int*)d_in[1];
    const float* Wk = (const float*)d_in[2];
    const float* bk = (const float*)d_in[3];
    const float* Wq = (const float*)d_in[4];
    const float* bq = (const float*)d_in[5];
    const float* Wv = (const float*)d_in[6];
    const float* bv = (const float*)d_in[7];
    const float* Wa = (const float*)d_in[8];
    const float* ba = (const float*)d_in[9];
    const float* skip = (const float*)d_in[10];
    const float* a_rel = (const float*)d_in[11];
    const float* m_rel = (const float*)d_in[12];
    const float* p_rel = (const float*)d_in[13];
    const float* ln_g = (const float*)d_in[14];
    const float* ln_b = (const float*)d_in[15];

    char* ws = (char*)d_ws;
    size_t off = 0;
    auto alloc = [&](size_t b) {
        size_t o = off;
        off = (off + b + 255) & ~(size_t)255;
        return o;
    };
    _Float16* xbA = (_Float16*)(ws + alloc((size_t)TT * NN * CC * 2));
    _Float16* xbB = (_Float16*)(ws + alloc((size_t)TT * NN * CC * 2));
    _Float16* qkv = (_Float16*)(ws + alloc((size_t)TT * NN * 384 * 2));
    _Float16* outg = (_Float16*)(ws + alloc((size_t)TT * NN * CC * 2));
    _Float16* W2 = (_Float16*)(ws + alloc((size_t)2 * TT * 384 * 128 * 2));
    _Float16* Wa2 = (_Float16*)(ws + alloc((size_t)2 * TT * 128 * 128 * 2));
    float* beff = (float*)(ws + alloc((size_t)2 * TT * 384 * 4));
    int* counts = (int*)(ws + alloc((size_t)2 * NN * 4));
    int* cursor = (int*)(ws + alloc((size_t)2 * NN * 4));
    int* rowptr = (int*)(ws + alloc((size_t)2 * (NN + 1) * 4));
    int* csr = (int*)(ws + alloc((size_t)2 * EE * 4));
    int* flag = (int*)(ws + alloc(256));
    int* bsum = (int*)(ws + alloc((size_t)2 * SCB * 4 + 256));
    (void)ws_size; (void)in_sizes; (void)n_in; (void)out_size;

    k_detect<<<1, 64, 0, stream>>>(ei, flag);
    (void)hipMemsetAsync(counts, 0, (size_t)2 * NN * 4, stream);
    k_count<<<(2 * EE + 255) / 256, 256, 0, stream>>>(ei, flag, counts);
    k_scan1<<<dim3(SCB, 2), 256, 0, stream>>>(counts, rowptr, bsum);
    k_scan2<<<1, 128, 0, stream>>>(bsum, rowptr);
    k_scan3<<<dim3(SCB, 2), 256, 0, stream>>>(rowptr, bsum, cursor);
    k_scatter<<<(2 * EE + 255) / 256, 256, 0, stream>>>(ei, flag, cursor, csr);
    k_cvt<<<(TT * NN * CC / 4 + 255) / 256, 256, 0, stream>>>((const float4*)x, (uint2*)xbA);
    k_prep<<<dim3((2 * 384 * 128 + 2 * 128 * 128 + 2 * 384 + 255) / 256, 2), 256, 0, stream>>>(
        Wk, Wq, Wv, Wa, bk, bq, bv, a_rel, m_rel, p_rel, W2, Wa2, beff);

    const int GB = (NN + 31) / 32;
    // layer 0: full qkv for both types
    k_gemm_qkv<6><<<dim3(GB, 2), 256, 0, stream>>>(xbA, W2, beff, qkv, 0, 0, 0);
    k_attn<<<dim3(NN / 4, 2), 256, 0, stream>>>(qkv, rowptr, csr, outg);
    k_epilogue<<<dim3((NN + 63) / 64, 2), 256, 0, stream>>>(
        outg, Wa2, ba, skip, ln_g, ln_b, xbA, xbB, nullptr, 0);
    // layer 1: only t0 output needed -> t0 needs q cols [0,128), t1 needs k/v cols [128,384)
    k_gemm_qkv<2><<<dim3(GB, 1), 256, 0, stream>>>(xbB, W2, beff, qkv, 1, 0, 0);
    k_gemm_qkv<4><<<dim3(GB, 1), 256, 0, stream>>>(xbB, W2, beff, qkv, 1, 1, 128);
    k_attn<<<dim3(NN / 4, 1), 256, 0, stream>>>(qkv, rowptr, csr, outg);
    k_epilogue<<<dim3((NN + 63) / 64, 1), 256, 0, stream>>>(
        outg, Wa2, ba, skip, ln_g, ln_b, xbB, nullptr, (float*)d_out, 1);
}

// Round 7
// 457.065 us; speedup vs baseline: 1.0852x; 1.0384x over previous
//
#include <hip/hip_runtime.h>

#define NN 50000
#define EE 400000
#define CC 128
#define TT 2

typedef float floatx4 __attribute__((ext_vector_type(4)));
typedef float floatx2 __attribute__((ext_vector_type(2)));
typedef _Float16 half8 __attribute__((ext_vector_type(8)));
typedef _Float16 half2t __attribute__((ext_vector_type(2)));

__device__ __forceinline__ unsigned pk2h(float a, float b) {
    return __builtin_bit_cast(unsigned, __builtin_amdgcn_cvt_pkrtz(a, b));
}
// tanh-approx gelu (jax.nn.gelu default approximate=True), NaN-free form
__device__ __forceinline__ float gelu_f(float x) {
    float u = 0.7978845608028654f * (x + 0.044715f * x * x * x);
    float t = __expf(2.f * u);
    return x * (1.f - 1.f / (t + 1.f));
}

// ---- OCP e4m3 pack/unpack (HW cvt on gfx950; SW fallback) ----
__device__ __forceinline__ unsigned pk_fp8x4(float a, float b, float c, float d) {
#if __has_builtin(__builtin_amdgcn_cvt_pk_fp8_f32)
    int v = 0;
    v = __builtin_amdgcn_cvt_pk_fp8_f32(a, b, v, false);
    v = __builtin_amdgcn_cvt_pk_fp8_f32(c, d, v, true);
    return (unsigned)v;
#else
    auto enc = [](float x) -> unsigned {
        unsigned u = __float_as_uint(x);
        unsigned s = (u >> 24) & 0x80;
        int e = (int)((u >> 23) & 0xff);
        unsigned m = u & 0x7fffff;
        if (e == 0) return s;
        int ne = e - 127 + 7;
        if (ne <= 0) {
            unsigned full = (1u << 23) | m;
            int sh = 21 - ne;
            if (sh > 24) return s;
            unsigned r = full >> sh;
            unsigned rem = full & ((1u << sh) - 1);
            unsigned half = 1u << (sh - 1);
            if (rem > half || (rem == half && (r & 1))) r++;
            return s | (r & 0x7f);
        }
        unsigned r = m >> 20;
        unsigned rem = m & 0xfffff;
        if (rem > 0x80000 || (rem == 0x80000 && (r & 1))) {
            r++;
            if (r == 8) { r = 0; ne++; }
        }
        if (ne > 15) return s | 0x7e;
        return s | ((unsigned)ne << 3) | r;
    };
    return enc(a) | (enc(b) << 8) | (enc(c) << 16) | (enc(d) << 24);
#endif
}

template <bool HI>
__device__ __forceinline__ floatx2 upk_fp8(unsigned v) {
#if __has_builtin(__builtin_amdgcn_cvt_pk_f32_fp8)
    return __builtin_amdgcn_cvt_pk_f32_fp8((int)v, HI);
#else
    auto dec = [](unsigned b) -> float {
        unsigned s = b & 0x80;
        unsigned e = (b >> 3) & 0xf;
        unsigned m = b & 7;
        float val;
        if (e == 0) val = (float)m * (1.f / 512.f);
        else val = (1.f + (float)m * 0.125f) * exp2f((float)e - 7.f);
        return s ? -val : val;
    };
    unsigned base = HI ? (v >> 16) : v;
    floatx2 r;
    r.x = dec(base & 0xff);
    r.y = dec((base >> 8) & 0xff);
    return r;
#endif
}

// ---- edge_index dtype probe: int64 arrays have zero high words ----
__global__ void k_detect(const int* __restrict__ ei, int* __restrict__ flag) {
    if (threadIdx.x == 0 && blockIdx.x == 0) {
        int orv = 0;
        for (int i = 1; i < 64; i += 2) orv |= ei[i];
        flag[0] = (orv == 0) ? 1 : 0;
    }
}

__global__ void k_count(const int* __restrict__ ei, const int* __restrict__ flag,
                        int* __restrict__ counts) {
    int i = blockIdx.x * 256 + threadIdx.x;
    if (i >= 2 * EE) return;
    int is64 = flag[0];
    int e = i / EE, j = i - e * EE;
    size_t pos = (size_t)(e * 2 + 1) * EE + j;
    int di = is64 ? ei[pos * 2] : ei[pos];
    di = min(max(di, 0), NN - 1);
    atomicAdd(&counts[e * NN + di], 1);
}

// ---- 3-phase scan: 49 blocks x 1024 elems per edge type ----
#define SCB ((NN + 1023) / 1024)
__global__ __launch_bounds__(256) void k_scan1(const int* __restrict__ counts,
                                               int* __restrict__ rowptr,
                                               int* __restrict__ bsum) {
    int e = blockIdx.y, b = blockIdx.x;
    int tid = threadIdx.x, lane = tid & 63, wid = tid >> 6;
    __shared__ int wsum[4];
    int base = b * 1024 + tid * 4;
    int v[4], s = 0;
#pragma unroll
    for (int k2 = 0; k2 < 4; k2++) {
        int i = base + k2;
        v[k2] = (i < NN) ? counts[e * NN + i] : 0;
        s += v[k2];
    }
    int incl = s;
#pragma unroll
    for (int off = 1; off < 64; off <<= 1) {
        int t2 = __shfl_up(incl, off);
        if (lane >= off) incl += t2;
    }
    if (lane == 63) wsum[wid] = incl;
    __syncthreads();
    int woff = 0;
    for (int w2 = 0; w2 < wid; w2++) woff += wsum[w2];
    int excl = woff + incl - s;
#pragma unroll
    for (int k2 = 0; k2 < 4; k2++) {
        int i = base + k2;
        if (i < NN) rowptr[e * (NN + 1) + i] = excl;
        excl += v[k2];
    }
    if (tid == 255) bsum[e * SCB + b] = woff + incl;
}

__global__ void k_scan2(int* __restrict__ bsum, int* __restrict__ rowptr) {
    int e = threadIdx.x >> 6, lane = threadIdx.x & 63;
    int v = (lane < SCB) ? bsum[e * SCB + lane] : 0;
    int incl = v;
#pragma unroll
    for (int off = 1; off < 64; off <<= 1) {
        int t2 = __shfl_up(incl, off);
        if (lane >= off) incl += t2;
    }
    if (lane < SCB) bsum[e * SCB + lane] = incl - v;
    if (lane == 63) rowptr[e * (NN + 1) + NN] = incl;
}

__global__ __launch_bounds__(256) void k_scan3(int* __restrict__ rowptr,
                                               const int* __restrict__ bsum,
                                               int* __restrict__ cursor) {
    int e = blockIdx.y, b = blockIdx.x;
    int off = bsum[e * SCB + b];
    int base = b * 1024 + threadIdx.x * 4;
#pragma unroll
    for (int k2 = 0; k2 < 4; k2++) {
        int i = base + k2;
        if (i < NN) {
            int r = rowptr[e * (NN + 1) + i] + off;
            rowptr[e * (NN + 1) + i] = r;
            cursor[e * NN + i] = r;
        }
    }
}

__global__ void k_scatter(const int* __restrict__ ei, const int* __restrict__ flag,
                          int* __restrict__ cursor, int* __restrict__ csr) {
    int i = blockIdx.x * 256 + threadIdx.x;
    if (i >= 2 * EE) return;
    int is64 = flag[0];
    int e = i / EE, j = i - e * EE;
    size_t ps = (size_t)(e * 2 + 0) * EE + j;
    size_t pd = (size_t)(e * 2 + 1) * EE + j;
    int si = is64 ? ei[ps * 2] : ei[ps];
    int di = is64 ? ei[pd * 2] : ei[pd];
    si = min(max(si, 0), NN - 1);
    di = min(max(di, 0), NN - 1);
    int pos = atomicAdd(&cursor[e * NN + di], 1);
    csr[(size_t)e * EE + pos] = si;
}

__global__ void k_cvt(const float4* __restrict__ x, uint2* __restrict__ xb) {
    int i = blockIdx.x * 256 + threadIdx.x;
    float4 v = x[i];
    uint2 o;
    o.x = pk2h(v.x, v.y);
    o.y = pk2h(v.z, v.w);
    xb[i] = o;
}

// Composed weights, both layers (l = blockIdx.y), A-frag row-major [m][k]:
//  W2[lt][n][k], n in [0,384): q*p_rel*scale | Wk∘a_rel | Wv∘m_rel ; k = input comp
__global__ void k_prep(const float* __restrict__ Wk, const float* __restrict__ Wq,
                       const float* __restrict__ Wv, const float* __restrict__ Wa,
                       const float* __restrict__ bk, const float* __restrict__ bq,
                       const float* __restrict__ bv,
                       const float* __restrict__ a_rel, const float* __restrict__ m_rel,
                       const float* __restrict__ p_rel,
                       _Float16* __restrict__ W2, _Float16* __restrict__ Wa2,
                       float* __restrict__ beff) {
    const float SCALE = 0.17677669529663687f;  // 1/sqrt(32)
    int l = blockIdx.y;
    int idx = blockIdx.x * 256 + threadIdx.x;
    if (idx < 2 * 384 * 128) {
        int t = idx / (384 * 128);
        int r = idx - t * 384 * 128;
        int n = r >> 7, k = r & 127;
        float val;
        if (n < 128) {
            val = Wq[((l * 2 + t) * 128 + k) * 128 + n] *
                  p_rel[(l * 2 + (1 - t)) * 4 + (n >> 5)] * SCALE;
        } else if (n < 256) {
            int nn = n - 128, h = nn >> 5, f = nn & 31;
            const float* wr = Wk + ((l * 2 + t) * 128 + k) * 128 + h * 32;
            const float* ar = a_rel + (((l * 2 + t) * 4 + h) * 32) * 32 + f;
            float s = 0.f;
            for (int d = 0; d < 32; d++) s += wr[d] * ar[d * 32];
            val = s;
        } else {
            int nn = n - 256, h = nn >> 5, f = nn & 31;
            const float* wr = Wv + ((l * 2 + t) * 128 + k) * 128 + h * 32;
            const float* mr = m_rel + (((l * 2 + t) * 4 + h) * 32) * 32 + f;
            float s = 0.f;
            for (int d = 0; d < 32; d++) s += wr[d] * mr[d * 32];
            val = s;
        }
        W2[((size_t)(l * 2 + t) * 384 + n) * 128 + k] = (_Float16)val;
    } else if (idx < 2 * 384 * 128 + 2 * 128 * 128) {
        int r = idx - 2 * 384 * 128;
        int t = r / (128 * 128);
        r -= t * 128 * 128;
        int n = r >> 7, k = r & 127;
        float val = Wa[((l * 2 + t) * 128 + k) * 128 + n];
        Wa2[((size_t)(l * 2 + t) * 128 + n) * 128 + k] = (_Float16)val;
    } else if (idx < 2 * 384 * 128 + 2 * 128 * 128 + 2 * 384) {
        int r = idx - (2 * 384 * 128 + 2 * 128 * 128);
        int t = r / 384, n = r - t * 384;
        float val;
        if (n < 128) {
            val = bq[(l * 2 + t) * 128 + n] * p_rel[(l * 2 + (1 - t)) * 4 + (n >> 5)] * SCALE;
        } else if (n < 256) {
            int nn = n - 128, h = nn >> 5, f = nn & 31;
            float s = 0.f;
            for (int d = 0; d < 32; d++)
                s += bk[(l * 2 + t) * 128 + h * 32 + d] *
                     a_rel[(((l * 2 + t) * 4 + h) * 32 + d) * 32 + f];
            val = s;
        } else {
            int nn = n - 256, h = nn >> 5, f = nn & 31;
            float s = 0.f;
            for (int d = 0; d < 32; d++)
                s += bv[(l * 2 + t) * 128 + h * 32 + d] *
                     m_rel[(((l * 2 + t) * 4 + h) * 32 + d) * 32 + f];
            val = s;
        }
        beff[(l * 2 + t) * 384 + n] = val;
    }
}

// Transposed GEMM + LDS-staged coalesced stores into mixed-precision qkv rows:
// node row = 512 B: [0,256) q f16 | [256,384) k fp8 | [384,512) v fp8.
// D[m=comp][n=node]; lane holds comps quad*4+{0..3} of node ln.
template <int NT, int COL0>
__global__ __launch_bounds__(256) void k_gemm_qkv(const _Float16* __restrict__ xb,
                                                  const _Float16* __restrict__ W2,
                                                  const float* __restrict__ beff,
                                                  unsigned char* __restrict__ qkv8, int l,
                                                  int t0) {
    constexpr int RB = (NT == 6) ? 512 : 256;  // tile row bytes
    constexpr int RS = RB + 16;                // LDS row stride (16B-aligned)
    __shared__ unsigned char tile[32 * RS];
    int t = t0 + blockIdx.y;
    int tid = threadIdx.x;
    int wid = tid >> 6, lane = tid & 63;
    int quad = lane >> 4, ln = lane & 15;
    int node0 = blockIdx.x * 32;
    const _Float16* Wt = W2 + (size_t)(l * 2 + t) * 384 * 128;
    half8 bf[2][4];
#pragma unroll
    for (int ns = 0; ns < 2; ns++) {
        int arow = min(node0 + ns * 16 + ln, NN - 1);
        const _Float16* xrow = xb + ((size_t)t * NN + arow) * CC;
#pragma unroll
        for (int kt = 0; kt < 4; kt++) bf[ns][kt] = *(const half8*)(xrow + kt * 32 + quad * 8);
    }
    floatx4 acc[NT][2];
#pragma unroll
    for (int nt = 0; nt < NT; nt++)
#pragma unroll
        for (int ns = 0; ns < 2; ns++) acc[nt][ns] = (floatx4){0.f, 0.f, 0.f, 0.f};
#pragma unroll
    for (int nt = 0; nt < NT; nt++) {
        int m = COL0 + wid * NT * 16 + nt * 16 + ln;
#pragma unroll
        for (int kt = 0; kt < 4; kt++) {
            half8 af = *(const half8*)(Wt + (size_t)m * 128 + kt * 32 + quad * 8);
            acc[nt][0] = __builtin_amdgcn_mfma_f32_16x16x32_f16(af, bf[0][kt], acc[nt][0], 0, 0, 0);
            acc[nt][1] = __builtin_amdgcn_mfma_f32_16x16x32_f16(af, bf[1][kt], acc[nt][1], 0, 0, 0);
        }
    }
    // stage to LDS (+bias): q comps -> f16 pairs, k/v comps -> fp8x4
#pragma unroll
    for (int nt = 0; nt < NT; nt++) {
        int c0 = COL0 + wid * NT * 16 + nt * 16 + quad * 4;
        float4 b4 = *(const float4*)(beff + (l * 2 + t) * 384 + c0);
#pragma unroll
        for (int ns = 0; ns < 2; ns++) {
            int nl = ns * 16 + ln;
            float v0 = acc[nt][ns][0] + b4.x, v1 = acc[nt][ns][1] + b4.y;
            float v2 = acc[nt][ns][2] + b4.z, v3 = acc[nt][ns][3] + b4.w;
            unsigned char* rowp = tile + nl * RS;
            if (c0 < 128) {
                uint2 o;
                o.x = pk2h(v0, v1);
                o.y = pk2h(v2, v3);
                *(uint2*)(rowp + 2 * c0) = o;
            } else {
                int loff = (COL0 == 128) ? (c0 - 128) : (128 + c0);  // 256+(c0-128)
                *(unsigned*)(rowp + loff) = pk_fp8x4(v0, v1, v2, v3);
            }
        }
    }
    __syncthreads();
    // coalesced copy-out: 16B chunks, contiguous RB bytes per node row
    constexpr int CPR = RB / 16;
    constexpr int PASSES = (32 * CPR) / 256;
#pragma unroll
    for (int p = 0; p < PASSES; p++) {
        int c = p * 256 + tid;
        int row = c / CPR, ch = c - row * CPR;
        int node = node0 + row;
        if (node < NN)
            *(uint4*)(qkv8 + ((size_t)t * NN + node) * 512 + (COL0 ? 256 : 0) + ch * 16) =
                *(const uint4*)(tile + row * RS + ch * 16);
    }
}

// Dest-centric attention.  Wave = 1 dest node; 64 lanes = 4 edge slots x 16 segs.
// q f16, k/v fp8 (HW unpack).  Writes RAW aggregate (gelu deferred).
__global__ __launch_bounds__(256) void k_attn(const unsigned char* __restrict__ qkv8,
                                              const int* __restrict__ rowptr,
                                              const int* __restrict__ csr,
                                              _Float16* __restrict__ outg) {
    int t = blockIdx.y;
    int e = 1 - t;
    int st = 1 - t;
    int wid = threadIdx.x >> 6, lane = threadIdx.x & 63;
    int n = blockIdx.x * 4 + wid;
    int e4 = lane >> 4, s = lane & 15;
    const unsigned char* qrow = qkv8 + ((size_t)t * NN + n) * 512;
    uint4 qd = *(const uint4*)(qrow + s * 16);
    float qf[8];
    {
        half2t h0 = __builtin_bit_cast(half2t, qd.x), h1 = __builtin_bit_cast(half2t, qd.y);
        half2t h2 = __builtin_bit_cast(half2t, qd.z), h3 = __builtin_bit_cast(half2t, qd.w);
        qf[0] = (float)h0.x; qf[1] = (float)h0.y;
        qf[2] = (float)h1.x; qf[3] = (float)h1.y;
        qf[4] = (float)h2.x; qf[5] = (float)h2.y;
        qf[6] = (float)h3.x; qf[7] = (float)h3.y;
    }
    int r0 = rowptr[e * (NN + 1) + n], r1 = rowptr[e * (NN + 1) + n + 1];
    r0 = __builtin_amdgcn_readfirstlane(r0);
    r1 = __builtin_amdgcn_readfirstlane(r1);
    const int* csrp = csr + (size_t)e * EE;
    const unsigned char* sbase = qkv8 + (size_t)st * NN * 512;
    float acc[8] = {0.f, 0.f, 0.f, 0.f, 0.f, 0.f, 0.f, 0.f};
    float lsum = 0.f;

    auto load_chunk = [&](int jj, uint2& kd, uint2& vd, float& msk) {
        int idx = min(jj + e4, r1 - 1);
        int si = csrp[idx];
        const unsigned char* row = sbase + (size_t)si * 512;
        kd = *(const uint2*)(row + 256 + s * 8);
        vd = *(const uint2*)(row + 384 + s * 8);
        msk = (jj + e4 < r1) ? 1.f : 0.f;
    };
    auto process = [&](const uint2& kd, const uint2& vd, float msk) {
        floatx2 k0 = upk_fp8<false>(kd.x), k1 = upk_fp8<true>(kd.x);
        floatx2 k2 = upk_fp8<false>(kd.y), k3 = upk_fp8<true>(kd.y);
        float p;
        p = qf[0] * k0.x;          p = fmaf(qf[1], k0.y, p);
        p = fmaf(qf[2], k1.x, p);  p = fmaf(qf[3], k1.y, p);
        p = fmaf(qf[4], k2.x, p);  p = fmaf(qf[5], k2.y, p);
        p = fmaf(qf[6], k3.x, p);  p = fmaf(qf[7], k3.y, p);
        p += __shfl_xor(p, 1);
        p += __shfl_xor(p, 2);  // 4 segs of one head now hold the full head dot
        float w = __expf(p) * msk;
        lsum += w;
        floatx2 v0 = upk_fp8<false>(vd.x), v1 = upk_fp8<true>(vd.x);
        floatx2 v2 = upk_fp8<false>(vd.y), v3 = upk_fp8<true>(vd.y);
        acc[0] = fmaf(w, v0.x, acc[0]);
        acc[1] = fmaf(w, v0.y, acc[1]);
        acc[2] = fmaf(w, v1.x, acc[2]);
        acc[3] = fmaf(w, v1.y, acc[3]);
        acc[4] = fmaf(w, v2.x, acc[4]);
        acc[5] = fmaf(w, v2.y, acc[5]);
        acc[6] = fmaf(w, v3.x, acc[6]);
        acc[7] = fmaf(w, v3.y, acc[7]);
    };

    if (r0 < r1) {
        uint2 kdA, vdA;
        float mA;
        load_chunk(r0, kdA, vdA, mA);
        int j = r0;
        for (; j + 4 < r1; j += 4) {
            uint2 kdB, vdB;
            float mB;
            load_chunk(j + 4, kdB, vdB, mB);  // prefetch next chunk
            process(kdA, vdA, mA);
            kdA = kdB; vdA = vdB; mA = mB;
        }
        process(kdA, vdA, mA);
    }
#pragma unroll
    for (int i = 0; i < 8; i++) {
        acc[i] += __shfl_xor(acc[i], 16);
        acc[i] += __shfl_xor(acc[i], 32);
    }
    lsum += __shfl_xor(lsum, 16);
    lsum += __shfl_xor(lsum, 32);
    float inv = 1.f / (lsum + 1e-16f);
    if (e4 == 0) {
        uint4 o;
        o.x = pk2h(acc[0] * inv, acc[1] * inv);
        o.y = pk2h(acc[2] * inv, acc[3] * inv);
        o.z = pk2h(acc[4] * inv, acc[5] * inv);
        o.w = pk2h(acc[6] * inv, acc[7] * inv);
        *(uint4*)(outg + ((size_t)t * NN + n) * CC + s * 8) = o;
    }
}

// Transposed epilogue with LDS-staged coalesced stores.
// o = gelu(outg) @ Wa + ba ; skip-blend ; LayerNorm ; ReLU.
__global__ __launch_bounds__(256) void k_epilogue(
    const _Float16* __restrict__ outg, const _Float16* __restrict__ Wa2,
    const float* __restrict__ ba, const float* __restrict__ skipv,
    const float* __restrict__ ln_g, const float* __restrict__ ln_b,
    const _Float16* __restrict__ xb_cur, _Float16* __restrict__ xb_next,
    float* __restrict__ xout, int l) {
    __shared__ float smem[64 * 130];  // f32 view: row stride 130; f16 view: stride 132
    _Float16* smem_h = (_Float16*)smem;
    int t = blockIdx.y;
    int tid = threadIdx.x;
    int wid = tid >> 6, lane = tid & 63;
    int quad = lane >> 4, ln = lane & 15;
    int node0 = blockIdx.x * 64;
    int nloc = wid * 16 + ln;
    int node = node0 + nloc;
    int arow = min(node, NN - 1);
    const _Float16* grow = outg + ((size_t)t * NN + arow) * CC;
    half8 bf[4];
#pragma unroll
    for (int kt = 0; kt < 4; kt++) {
        uint4 gd = *(const uint4*)(grow + kt * 32 + quad * 8);
        half2t h0 = __builtin_bit_cast(half2t, gd.x), h1 = __builtin_bit_cast(half2t, gd.y);
        half2t h2 = __builtin_bit_cast(half2t, gd.z), h3 = __builtin_bit_cast(half2t, gd.w);
        uint4 pk;
        pk.x = pk2h(gelu_f((float)h0.x), gelu_f((float)h0.y));
        pk.y = pk2h(gelu_f((float)h1.x), gelu_f((float)h1.y));
        pk.z = pk2h(gelu_f((float)h2.x), gelu_f((float)h2.y));
        pk.w = pk2h(gelu_f((float)h3.x), gelu_f((float)h3.y));
        bf[kt] = __builtin_bit_cast(half8, pk);
    }
    const _Float16* Wt = Wa2 + (size_t)(l * 2 + t) * 128 * 128;
    floatx4 acc[8];
#pragma unroll
    for (int nt = 0; nt < 8; nt++) acc[nt] = (floatx4){0.f, 0.f, 0.f, 0.f};
#pragma unroll
    for (int nt = 0; nt < 8; nt++) {
        int m = nt * 16 + ln;
#pragma unroll
        for (int kt = 0; kt < 4; kt++) {
            half8 af = *(const half8*)(Wt + (size_t)m * 128 + kt * 32 + quad * 8);
            acc[nt] = __builtin_amdgcn_mfma_f32_16x16x32_f16(af, bf[kt], acc[nt], 0, 0, 0);
        }
    }
    float sv = skipv[l * TT + t];
    float beta = 1.f / (1.f + __expf(-sv));
    const _Float16* xrow = xb_cur + ((size_t)t * NN + arow) * CC;
    float xn[8][4];
    float s1 = 0.f, s2 = 0.f;
#pragma unroll
    for (int nt = 0; nt < 8; nt++) {
        int c0 = nt * 16 + quad * 4;
        float4 b4 = *(const float4*)(ba + (l * TT + t) * CC + c0);
        uint2 xw = *(const uint2*)(xrow + c0);
        half2t x0 = __builtin_bit_cast(half2t, xw.x), x1 = __builtin_bit_cast(half2t, xw.y);
        float xv[4] = {(float)x0.x, (float)x0.y, (float)x1.x, (float)x1.y};
        float bb[4] = {b4.x, b4.y, b4.z, b4.w};
#pragma unroll
        for (int reg = 0; reg < 4; reg++) {
            float o = acc[nt][reg] + bb[reg];
            float v = beta * o + (1.f - beta) * xv[reg];
            xn[nt][reg] = v;
            s1 += v;
            s2 += v * v;
        }
    }
    s1 += __shfl_xor(s1, 16); s1 += __shfl_xor(s1, 32);
    s2 += __shfl_xor(s2, 16); s2 += __shfl_xor(s2, 32);
    float mu = s1 * (1.f / CC);
    float var = s2 * (1.f / CC) - mu * mu;
    float rs = rsqrtf(var + 1e-5f);
#pragma unroll
    for (int nt = 0; nt < 8; nt++) {
        int c0 = nt * 16 + quad * 4;
        float4 g4 = *(const float4*)(ln_g + (l * TT + t) * CC + c0);
        float4 be4 = *(const float4*)(ln_b + (l * TT + t) * CC + c0);
        float y0 = fmaxf((xn[nt][0] - mu) * rs * g4.x + be4.x, 0.f);
        float y1 = fmaxf((xn[nt][1] - mu) * rs * g4.y + be4.y, 0.f);
        float y2 = fmaxf((xn[nt][2] - mu) * rs * g4.z + be4.z, 0.f);
        float y3 = fmaxf((xn[nt][3] - mu) * rs * g4.w + be4.w, 0.f);
        if (xout) {
            float4 o4 = {y0, y1, y2, y3};
            *(float4*)(smem + nloc * 130 + c0) = o4;
        } else {
            uint2 o;
            o.x = pk2h(y0, y1);
            o.y = pk2h(y2, y3);
            *(uint2*)(smem_h + nloc * 132 + c0) = o;
        }
    }
    __syncthreads();
    if (xout) {
#pragma unroll
        for (int p = 0; p < 8; p++) {
            int c = p * 256 + tid;
            int row = c >> 5, ch = c & 31;
            int nd = node0 + row;
            if (nd < NN)
                *(uint4*)(xout + (size_t)nd * CC + ch * 4) =
                    *(const uint4*)(smem + row * 130 + ch * 4);
        }
    } else {
#pragma unroll
        for (int p = 0; p < 4; p++) {
            int c = p * 256 + tid;
            int row = c >> 4, ch = c & 15;
            int nd = node0 + row;
            if (nd < NN)
                *(uint4*)(xb_next + ((size_t)t * NN + nd) * CC + ch * 8) =
                    *(const uint4*)(smem_h + row * 132 + ch * 8);
        }
    }
}

extern "C" void kernel_launch(void* const* d_in, const int* in_sizes, int n_in,
                              void* d_out, int out_size, void* d_ws, size_t ws_size,
                              hipStream_t stream) {
    const float* x = (const float*)d_in[0];
    const int* ei = (const int*)d_in[1];
    const float* Wk = (const float*)d_in[2];
    const float* bk = (const float*)d_in[3];
    const float* Wq = (const float*)d_in[4];
    const float* bq = (const float*)d_in[5];
    const float* Wv = (const float*)d_in[6];
    const float* bv = (const float*)d_in[7];
    const float* Wa = (const float*)d_in[8];
    const float* ba = (const float*)d_in[9];
    const float* skip = (const float*)d_in[10];
    const float* a_rel = (const float*)d_in[11];
    const float* m_rel = (const float*)d_in[12];
    const float* p_rel = (const float*)d_in[13];
    const float* ln_g = (const float*)d_in[14];
    const float* ln_b = (const float*)d_in[15];

    char* ws = (char*)d_ws;
    size_t off = 0;
    auto alloc = [&](size_t b) {
        size_t o = off;
        off = (off + b + 255) & ~(size_t)255;
        return o;
    };
    _Float16* xbA = (_Float16*)(ws + alloc((size_t)TT * NN * CC * 2));
    _Float16* xbB = (_Float16*)(ws + alloc((size_t)TT * NN * CC * 2));
    unsigned char* qkv8 = (unsigned char*)(ws + alloc((size_t)TT * NN * 512));
    _Float16* outg = (_Float16*)(ws + alloc((size_t)TT * NN * CC * 2));
    _Float16* W2 = (_Float16*)(ws + alloc((size_t)2 * TT * 384 * 128 * 2));
    _Float16* Wa2 = (_Float16*)(ws + alloc((size_t)2 * TT * 128 * 128 * 2));
    float* beff = (float*)(ws + alloc((size_t)2 * TT * 384 * 4));
    int* counts = (int*)(ws + alloc((size_t)2 * NN * 4));
    int* cursor = (int*)(ws + alloc((size_t)2 * NN * 4));
    int* rowptr = (int*)(ws + alloc((size_t)2 * (NN + 1) * 4));
    int* csr = (int*)(ws + alloc((size_t)2 * EE * 4));
    int* flag = (int*)(ws + alloc(256));
    int* bsum = (int*)(ws + alloc((size_t)2 * SCB * 4 + 256));
    (void)ws_size; (void)in_sizes; (void)n_in; (void)out_size;

    k_detect<<<1, 64, 0, stream>>>(ei, flag);
    (void)hipMemsetAsync(counts, 0, (size_t)2 * NN * 4, stream);
    k_count<<<(2 * EE + 255) / 256, 256, 0, stream>>>(ei, flag, counts);
    k_scan1<<<dim3(SCB, 2), 256, 0, stream>>>(counts, rowptr, bsum);
    k_scan2<<<1, 128, 0, stream>>>(bsum, rowptr);
    k_scan3<<<dim3(SCB, 2), 256, 0, stream>>>(rowptr, bsum, cursor);
    k_scatter<<<(2 * EE + 255) / 256, 256, 0, stream>>>(ei, flag, cursor, csr);
    k_cvt<<<(TT * NN * CC / 4 + 255) / 256, 256, 0, stream>>>((const float4*)x, (uint2*)xbA);
    k_prep<<<dim3((2 * 384 * 128 + 2 * 128 * 128 + 2 * 384 + 255) / 256, 2), 256, 0, stream>>>(
        Wk, Wq, Wv, Wa, bk, bq, bv, a_rel, m_rel, p_rel, W2, Wa2, beff);

    const int GB = (NN + 31) / 32;
    // layer 0: full qkv for both types
    k_gemm_qkv<6, 0><<<dim3(GB, 2), 256, 0, stream>>>(xbA, W2, beff, qkv8, 0, 0);
    k_attn<<<dim3(NN / 4, 2), 256, 0, stream>>>(qkv8, rowptr, csr, outg);
    k_epilogue<<<dim3((NN + 63) / 64, 2), 256, 0, stream>>>(
        outg, Wa2, ba, skip, ln_g, ln_b, xbA, xbB, nullptr, 0);
    // layer 1: only t0 output needed -> t0 needs q cols [0,128), t1 needs k/v cols [128,384)
    k_gemm_qkv<2, 0><<<dim3(GB, 1), 256, 0, stream>>>(xbB, W2, beff, qkv8, 1, 0);
    k_gemm_qkv<4, 128><<<dim3(GB, 1), 256, 0, stream>>>(xbB, W2, beff, qkv8, 1, 1);
    k_attn<<<dim3(NN / 4, 1), 256, 0, stream>>>(qkv8, rowptr, csr, outg);
    k_epilogue<<<dim3((NN + 63) / 64, 1), 256, 0, stream>>>(
        outg, Wa2, ba, skip, ln_g, ln_b, xbB, nullptr, (float*)d_out, 1);
}

// Round 8
// 386.345 us; speedup vs baseline: 1.2839x; 1.1830x over previous
//
#include <hip/hip_runtime.h>

#define NN 50000
#define EE 400000
#define CC 128
#define TT 2
#define NT16R 3128  // padded 16-node tiles per type (ceil(50048/16))

typedef float floatx4 __attribute__((ext_vector_type(4)));
typedef float floatx2 __attribute__((ext_vector_type(2)));
typedef _Float16 half8 __attribute__((ext_vector_type(8)));
typedef _Float16 half2t __attribute__((ext_vector_type(2)));

__device__ __forceinline__ unsigned pk2h(float a, float b) {
    return __builtin_bit_cast(unsigned, __builtin_amdgcn_cvt_pkrtz(a, b));
}
// tanh-approx gelu (jax.nn.gelu default approximate=True), NaN-free form
__device__ __forceinline__ float gelu_f(float x) {
    float u = 0.7978845608028654f * (x + 0.044715f * x * x * x);
    float t = __expf(2.f * u);
    return x * (1.f - 1.f / (t + 1.f));
}

// ---- OCP e4m3 pack/unpack (HW cvt on gfx950; SW fallback) ----
__device__ __forceinline__ unsigned pk_fp8x4(float a, float b, float c, float d) {
#if __has_builtin(__builtin_amdgcn_cvt_pk_fp8_f32)
    int v = 0;
    v = __builtin_amdgcn_cvt_pk_fp8_f32(a, b, v, false);
    v = __builtin_amdgcn_cvt_pk_fp8_f32(c, d, v, true);
    return (unsigned)v;
#else
    auto enc = [](float x) -> unsigned {
        unsigned u = __float_as_uint(x);
        unsigned s = (u >> 24) & 0x80;
        int e = (int)((u >> 23) & 0xff);
        unsigned m = u & 0x7fffff;
        if (e == 0) return s;
        int ne = e - 127 + 7;
        if (ne <= 0) {
            unsigned full = (1u << 23) | m;
            int sh = 21 - ne;
            if (sh > 24) return s;
            unsigned r = full >> sh;
            unsigned rem = full & ((1u << sh) - 1);
            unsigned half = 1u << (sh - 1);
            if (rem > half || (rem == half && (r & 1))) r++;
            return s | (r & 0x7f);
        }
        unsigned r = m >> 20;
        unsigned rem = m & 0xfffff;
        if (rem > 0x80000 || (rem == 0x80000 && (r & 1))) {
            r++;
            if (r == 8) { r = 0; ne++; }
        }
        if (ne > 15) return s | 0x7e;
        return s | ((unsigned)ne << 3) | r;
    };
    return enc(a) | (enc(b) << 8) | (enc(c) << 16) | (enc(d) << 24);
#endif
}

template <bool HI>
__device__ __forceinline__ floatx2 upk_fp8(unsigned v) {
#if __has_builtin(__builtin_amdgcn_cvt_pk_f32_fp8)
    return __builtin_amdgcn_cvt_pk_f32_fp8((int)v, HI);
#else
    auto dec = [](unsigned b) -> float {
        unsigned s = b & 0x80;
        unsigned e = (b >> 3) & 0xf;
        unsigned m = b & 7;
        float val;
        if (e == 0) val = (float)m * (1.f / 512.f);
        else val = (1.f + (float)m * 0.125f) * exp2f((float)e - 7.f);
        return s ? -val : val;
    };
    unsigned base = HI ? (v >> 16) : v;
    floatx2 r;
    r.x = dec(base & 0xff);
    r.y = dec((base >> 8) & 0xff);
    return r;
#endif
}

// ---- edge_index dtype probe: int64 arrays have zero high words ----
__global__ void k_detect(const int* __restrict__ ei, int* __restrict__ flag) {
    if (threadIdx.x == 0 && blockIdx.x == 0) {
        int orv = 0;
        for (int i = 1; i < 64; i += 2) orv |= ei[i];
        flag[0] = (orv == 0) ? 1 : 0;
    }
}

__global__ void k_count(const int* __restrict__ ei, const int* __restrict__ flag,
                        int* __restrict__ counts) {
    int i = blockIdx.x * 256 + threadIdx.x;
    if (i >= 2 * EE) return;
    int is64 = flag[0];
    int e = i / EE, j = i - e * EE;
    size_t pos = (size_t)(e * 2 + 1) * EE + j;
    int di = is64 ? ei[pos * 2] : ei[pos];
    di = min(max(di, 0), NN - 1);
    atomicAdd(&counts[e * NN + di], 1);
}

// ---- 3-phase scan: 49 blocks x 1024 elems per edge type ----
#define SCB ((NN + 1023) / 1024)
__global__ __launch_bounds__(256) void k_scan1(const int* __restrict__ counts,
                                               int* __restrict__ rowptr,
                                               int* __restrict__ bsum) {
    int e = blockIdx.y, b = blockIdx.x;
    int tid = threadIdx.x, lane = tid & 63, wid = tid >> 6;
    __shared__ int wsum[4];
    int base = b * 1024 + tid * 4;
    int v[4], s = 0;
#pragma unroll
    for (int k2 = 0; k2 < 4; k2++) {
        int i = base + k2;
        v[k2] = (i < NN) ? counts[e * NN + i] : 0;
        s += v[k2];
    }
    int incl = s;
#pragma unroll
    for (int off = 1; off < 64; off <<= 1) {
        int t2 = __shfl_up(incl, off);
        if (lane >= off) incl += t2;
    }
    if (lane == 63) wsum[wid] = incl;
    __syncthreads();
    int woff = 0;
    for (int w2 = 0; w2 < wid; w2++) woff += wsum[w2];
    int excl = woff + incl - s;
#pragma unroll
    for (int k2 = 0; k2 < 4; k2++) {
        int i = base + k2;
        if (i < NN) rowptr[e * (NN + 1) + i] = excl;
        excl += v[k2];
    }
    if (tid == 255) bsum[e * SCB + b] = woff + incl;
}

__global__ void k_scan2(int* __restrict__ bsum, int* __restrict__ rowptr) {
    int e = threadIdx.x >> 6, lane = threadIdx.x & 63;
    int v = (lane < SCB) ? bsum[e * SCB + lane] : 0;
    int incl = v;
#pragma unroll
    for (int off = 1; off < 64; off <<= 1) {
        int t2 = __shfl_up(incl, off);
        if (lane >= off) incl += t2;
    }
    if (lane < SCB) bsum[e * SCB + lane] = incl - v;
    if (lane == 63) rowptr[e * (NN + 1) + NN] = incl;
}

__global__ __launch_bounds__(256) void k_scan3(int* __restrict__ rowptr,
                                               const int* __restrict__ bsum,
                                               int* __restrict__ cursor) {
    int e = blockIdx.y, b = blockIdx.x;
    int off = bsum[e * SCB + b];
    int base = b * 1024 + threadIdx.x * 4;
#pragma unroll
    for (int k2 = 0; k2 < 4; k2++) {
        int i = base + k2;
        if (i < NN) {
            int r = rowptr[e * (NN + 1) + i] + off;
            rowptr[e * (NN + 1) + i] = r;
            cursor[e * NN + i] = r;
        }
    }
}

__global__ void k_scatter(const int* __restrict__ ei, const int* __restrict__ flag,
                          int* __restrict__ cursor, int* __restrict__ csr) {
    int i = blockIdx.x * 256 + threadIdx.x;
    if (i >= 2 * EE) return;
    int is64 = flag[0];
    int e = i / EE, j = i - e * EE;
    size_t ps = (size_t)(e * 2 + 0) * EE + j;
    size_t pd = (size_t)(e * 2 + 1) * EE + j;
    int si = is64 ? ei[ps * 2] : ei[ps];
    int di = is64 ? ei[pd * 2] : ei[pd];
    si = min(max(si, 0), NN - 1);
    di = min(max(di, 0), NN - 1);
    int pos = atomicAdd(&cursor[e * NN + di], 1);
    csr[(size_t)e * EE + pos] = si;
}

// x f32 row-major -> xs f16 swizzled [t][tile][kt][quad][ln][8] via LDS transpose.
// Both global sides fully coalesced.  Pad tiles filled with clamped rows.
__global__ __launch_bounds__(256) void k_cvt(const float* __restrict__ x,
                                             _Float16* __restrict__ xs) {
    __shared__ _Float16 sm[64 * 132];
    int t = blockIdx.y;
    int tid = threadIdx.x;
    int node0 = blockIdx.x * 64;
#pragma unroll
    for (int p = 0; p < 8; p++) {
        int c = p * 256 + tid;
        int row = c >> 5, ch = c & 31;
        int node = min(node0 + row, NN - 1);
        float4 v = *(const float4*)(x + ((size_t)t * NN + node) * CC + ch * 4);
        uint2 o;
        o.x = pk2h(v.x, v.y);
        o.y = pk2h(v.z, v.w);
        *(uint2*)(sm + row * 132 + ch * 4) = o;
    }
    __syncthreads();
    _Float16* xt = xs + (size_t)t * NT16R * 2048;
#pragma unroll
    for (int p = 0; p < 4; p++) {
        int c = p * 256 + tid;
        int tl = c >> 8, kt = (c >> 6) & 3, l = c & 63;
        int q = l >> 4, ln = l & 15;
        *(uint4*)(xt + ((size_t)(blockIdx.x * 4 + tl) * 4 + kt) * 512 + l * 8) =
            *(const uint4*)(sm + (tl * 16 + ln) * 132 + kt * 32 + q * 8);
    }
}

// Composed weights, both layers (l = blockIdx.y), swizzled A-frag layout:
//  W2[lt][mt(24)][kt(4)][lane(64)][8]; m = mt*16+(lane&15), k = kt*32+(lane>>4)*8+j.
//  n in [0,384): q*p_rel*scale | Wk∘a_rel | Wv∘m_rel
__global__ void k_prep(const float* __restrict__ Wk, const float* __restrict__ Wq,
                       const float* __restrict__ Wv, const float* __restrict__ Wa,
                       const float* __restrict__ bk, const float* __restrict__ bq,
                       const float* __restrict__ bv,
                       const float* __restrict__ a_rel, const float* __restrict__ m_rel,
                       const float* __restrict__ p_rel,
                       _Float16* __restrict__ W2, _Float16* __restrict__ Wa2,
                       float* __restrict__ beff) {
    const float SCALE = 0.17677669529663687f;  // 1/sqrt(32)
    int l = blockIdx.y;
    int idx = blockIdx.x * 256 + threadIdx.x;
    if (idx < 2 * 384 * 128) {
        int t = idx / (384 * 128);
        int r = idx - t * 384 * 128;
        int n = r >> 7, k = r & 127;
        float val;
        if (n < 128) {
            val = Wq[((l * 2 + t) * 128 + k) * 128 + n] *
                  p_rel[(l * 2 + (1 - t)) * 4 + (n >> 5)] * SCALE;
        } else if (n < 256) {
            int nn = n - 128, h = nn >> 5, f = nn & 31;
            const float* wr = Wk + ((l * 2 + t) * 128 + k) * 128 + h * 32;
            const float* ar = a_rel + (((l * 2 + t) * 4 + h) * 32) * 32 + f;
            float s = 0.f;
            for (int d = 0; d < 32; d++) s += wr[d] * ar[d * 32];
            val = s;
        } else {
            int nn = n - 256, h = nn >> 5, f = nn & 31;
            const float* wr = Wv + ((l * 2 + t) * 128 + k) * 128 + h * 32;
            const float* mr = m_rel + (((l * 2 + t) * 4 + h) * 32) * 32 + f;
            float s = 0.f;
            for (int d = 0; d < 32; d++) s += wr[d] * mr[d * 32];
            val = s;
        }
        W2[(((size_t)(l * 2 + t) * 24 + (n >> 4)) * 4 + (k >> 5)) * 512 +
           (((k & 31) >> 3) * 16 + (n & 15)) * 8 + (k & 7)] = (_Float16)val;
    } else if (idx < 2 * 384 * 128 + 2 * 128 * 128) {
        int r = idx - 2 * 384 * 128;
        int t = r / (128 * 128);
        r -= t * 128 * 128;
        int n = r >> 7, k = r & 127;
        float val = Wa[((l * 2 + t) * 128 + k) * 128 + n];
        Wa2[(((size_t)(l * 2 + t) * 8 + (n >> 4)) * 4 + (k >> 5)) * 512 +
            (((k & 31) >> 3) * 16 + (n & 15)) * 8 + (k & 7)] = (_Float16)val;
    } else if (idx < 2 * 384 * 128 + 2 * 128 * 128 + 2 * 384) {
        int r = idx - (2 * 384 * 128 + 2 * 128 * 128);
        int t = r / 384, n = r - t * 384;
        float val;
        if (n < 128) {
            val = bq[(l * 2 + t) * 128 + n] * p_rel[(l * 2 + (1 - t)) * 4 + (n >> 5)] * SCALE;
        } else if (n < 256) {
            int nn = n - 128, h = nn >> 5, f = nn & 31;
            float s = 0.f;
            for (int d = 0; d < 32; d++)
                s += bk[(l * 2 + t) * 128 + h * 32 + d] *
                     a_rel[(((l * 2 + t) * 4 + h) * 32 + d) * 32 + f];
            val = s;
        } else {
            int nn = n - 256, h = nn >> 5, f = nn & 31;
            float s = 0.f;
            for (int d = 0; d < 32; d++)
                s += bv[(l * 2 + t) * 128 + h * 32 + d] *
                     m_rel[(((l * 2 + t) * 4 + h) * 32 + d) * 32 + f];
            val = s;
        }
        beff[(l * 2 + t) * 384 + n] = val;
    }
}

// Transposed GEMM, swizzled operands (every frag load = base + lane*16, coalesced),
// LDS-staged coalesced stores into mixed-precision qkv rows:
// node row = 512 B: [0,256) q f16 | [256,384) k fp8 | [384,512) v fp8.
template <int NT, int COL0>
__global__ __launch_bounds__(256) void k_gemm_qkv(const _Float16* __restrict__ xs,
                                                  const _Float16* __restrict__ W2,
                                                  const float* __restrict__ beff,
                                                  unsigned char* __restrict__ qkv8, int l,
                                                  int t0) {
    constexpr int RB = (NT == 6) ? 512 : 256;  // tile row bytes
    constexpr int RS = RB + 16;                // LDS row stride
    __shared__ unsigned char tile[32 * RS];
    int t = t0 + blockIdx.y;
    int tid = threadIdx.x;
    int wid = tid >> 6, lane = tid & 63;
    int quad = lane >> 4, ln = lane & 15;
    int node0 = blockIdx.x * 32;
    int tile0 = blockIdx.x * 2;
    int lt = l * 2 + t;
    const _Float16* Wt = W2 + (size_t)lt * 24 * 2048;
    const _Float16* xt = xs + (size_t)t * NT16R * 2048;
    half8 bf[2][4];
#pragma unroll
    for (int ns = 0; ns < 2; ns++)
#pragma unroll
        for (int kt = 0; kt < 4; kt++)
            bf[ns][kt] = *(const half8*)(xt + ((size_t)(tile0 + ns) * 4 + kt) * 512 + lane * 8);
    floatx4 acc[NT][2];
#pragma unroll
    for (int nt = 0; nt < NT; nt++)
#pragma unroll
        for (int ns = 0; ns < 2; ns++) acc[nt][ns] = (floatx4){0.f, 0.f, 0.f, 0.f};
#pragma unroll
    for (int nt = 0; nt < NT; nt++) {
        int mt = COL0 / 16 + wid * NT + nt;
#pragma unroll
        for (int kt = 0; kt < 4; kt++) {
            half8 af = *(const half8*)(Wt + ((size_t)mt * 4 + kt) * 512 + lane * 8);
            acc[nt][0] = __builtin_amdgcn_mfma_f32_16x16x32_f16(af, bf[0][kt], acc[nt][0], 0, 0, 0);
            acc[nt][1] = __builtin_amdgcn_mfma_f32_16x16x32_f16(af, bf[1][kt], acc[nt][1], 0, 0, 0);
        }
    }
    // stage to LDS (+bias): q comps -> f16 pairs, k/v comps -> fp8x4
#pragma unroll
    for (int nt = 0; nt < NT; nt++) {
        int c0 = COL0 + wid * NT * 16 + nt * 16 + quad * 4;
        float4 b4 = *(const float4*)(beff + (l * 2 + t) * 384 + c0);
#pragma unroll
        for (int ns = 0; ns < 2; ns++) {
            int nl = ns * 16 + ln;
            float v0 = acc[nt][ns][0] + b4.x, v1 = acc[nt][ns][1] + b4.y;
            float v2 = acc[nt][ns][2] + b4.z, v3 = acc[nt][ns][3] + b4.w;
            unsigned char* rowp = tile + nl * RS;
            if (c0 < 128) {
                uint2 o;
                o.x = pk2h(v0, v1);
                o.y = pk2h(v2, v3);
                *(uint2*)(rowp + 2 * c0) = o;
            } else {
                int loff = (COL0 == 128) ? (c0 - 128) : (128 + c0);  // 256+(c0-128)
                *(unsigned*)(rowp + loff) = pk_fp8x4(v0, v1, v2, v3);
            }
        }
    }
    __syncthreads();
    // coalesced copy-out: 16B chunks, contiguous RB bytes per node row
    constexpr int CPR = RB / 16;
    constexpr int PASSES = (32 * CPR) / 256;
#pragma unroll
    for (int p = 0; p < PASSES; p++) {
        int c = p * 256 + tid;
        int row = c / CPR, ch = c - row * CPR;
        int node = node0 + row;
        if (node < NN)
            *(uint4*)(qkv8 + ((size_t)t * NN + node) * 512 + (COL0 ? 256 : 0) + ch * 16) =
                *(const uint4*)(tile + row * RS + ch * 16);
    }
}

// Dest-centric attention.  Wave = 1 dest node; 64 lanes = 4 edge slots x 16 segs.
// q f16, k/v fp8 (HW unpack).  Writes RAW aggregate (gelu deferred).
__global__ __launch_bounds__(256) void k_attn(const unsigned char* __restrict__ qkv8,
                                              const int* __restrict__ rowptr,
                                              const int* __restrict__ csr,
                                              _Float16* __restrict__ outg) {
    int t = blockIdx.y;
    int e = 1 - t;
    int st = 1 - t;
    int wid = threadIdx.x >> 6, lane = threadIdx.x & 63;
    int n = blockIdx.x * 4 + wid;
    int e4 = lane >> 4, s = lane & 15;
    const unsigned char* qrow = qkv8 + ((size_t)t * NN + n) * 512;
    uint4 qd = *(const uint4*)(qrow + s * 16);
    float qf[8];
    {
        half2t h0 = __builtin_bit_cast(half2t, qd.x), h1 = __builtin_bit_cast(half2t, qd.y);
        half2t h2 = __builtin_bit_cast(half2t, qd.z), h3 = __builtin_bit_cast(half2t, qd.w);
        qf[0] = (float)h0.x; qf[1] = (float)h0.y;
        qf[2] = (float)h1.x; qf[3] = (float)h1.y;
        qf[4] = (float)h2.x; qf[5] = (float)h2.y;
        qf[6] = (float)h3.x; qf[7] = (float)h3.y;
    }
    int r0 = rowptr[e * (NN + 1) + n], r1 = rowptr[e * (NN + 1) + n + 1];
    r0 = __builtin_amdgcn_readfirstlane(r0);
    r1 = __builtin_amdgcn_readfirstlane(r1);
    const int* csrp = csr + (size_t)e * EE;
    const unsigned char* sbase = qkv8 + (size_t)st * NN * 512;
    float acc[8] = {0.f, 0.f, 0.f, 0.f, 0.f, 0.f, 0.f, 0.f};
    float lsum = 0.f;

    auto load_chunk = [&](int jj, uint2& kd, uint2& vd, float& msk) {
        int idx = min(jj + e4, r1 - 1);
        int si = csrp[idx];
        const unsigned char* row = sbase + (size_t)si * 512;
        kd = *(const uint2*)(row + 256 + s * 8);
        vd = *(const uint2*)(row + 384 + s * 8);
        msk = (jj + e4 < r1) ? 1.f : 0.f;
    };
    auto process = [&](const uint2& kd, const uint2& vd, float msk) {
        floatx2 k0 = upk_fp8<false>(kd.x), k1 = upk_fp8<true>(kd.x);
        floatx2 k2 = upk_fp8<false>(kd.y), k3 = upk_fp8<true>(kd.y);
        float p;
        p = qf[0] * k0.x;          p = fmaf(qf[1], k0.y, p);
        p = fmaf(qf[2], k1.x, p);  p = fmaf(qf[3], k1.y, p);
        p = fmaf(qf[4], k2.x, p);  p = fmaf(qf[5], k2.y, p);
        p = fmaf(qf[6], k3.x, p);  p = fmaf(qf[7], k3.y, p);
        p += __shfl_xor(p, 1);
        p += __shfl_xor(p, 2);  // 4 segs of one head now hold the full head dot
        float w = __expf(p) * msk;
        lsum += w;
        floatx2 v0 = upk_fp8<false>(vd.x), v1 = upk_fp8<true>(vd.x);
        floatx2 v2 = upk_fp8<false>(vd.y), v3 = upk_fp8<true>(vd.y);
        acc[0] = fmaf(w, v0.x, acc[0]);
        acc[1] = fmaf(w, v0.y, acc[1]);
        acc[2] = fmaf(w, v1.x, acc[2]);
        acc[3] = fmaf(w, v1.y, acc[3]);
        acc[4] = fmaf(w, v2.x, acc[4]);
        acc[5] = fmaf(w, v2.y, acc[5]);
        acc[6] = fmaf(w, v3.x, acc[6]);
        acc[7] = fmaf(w, v3.y, acc[7]);
    };

    if (r0 < r1) {
        uint2 kdA, vdA;
        float mA;
        load_chunk(r0, kdA, vdA, mA);
        int j = r0;
        for (; j + 4 < r1; j += 4) {
            uint2 kdB, vdB;
            float mB;
            load_chunk(j + 4, kdB, vdB, mB);  // prefetch next chunk
            process(kdA, vdA, mA);
            kdA = kdB; vdA = vdB; mA = mB;
        }
        process(kdA, vdA, mA);
    }
#pragma unroll
    for (int i = 0; i < 8; i++) {
        acc[i] += __shfl_xor(acc[i], 16);
        acc[i] += __shfl_xor(acc[i], 32);
    }
    lsum += __shfl_xor(lsum, 16);
    lsum += __shfl_xor(lsum, 32);
    float inv = 1.f / (lsum + 1e-16f);
    if (e4 == 0) {
        uint4 o;
        o.x = pk2h(acc[0] * inv, acc[1] * inv);
        o.y = pk2h(acc[2] * inv, acc[3] * inv);
        o.z = pk2h(acc[4] * inv, acc[5] * inv);
        o.w = pk2h(acc[6] * inv, acc[7] * inv);
        *(uint4*)(outg + ((size_t)t * NN + n) * CC + s * 8) = o;
    }
}

// Transposed epilogue, swizzled Wa/x operands, LDS-staged coalesced stores.
// o = gelu(outg) @ Wa + ba ; skip-blend ; LayerNorm ; ReLU.
// f16 path writes xb_next in swizzled layout; f32 path (l=1) row-major d_out.
__global__ __launch_bounds__(256) void k_epilogue(
    const _Float16* __restrict__ outg, const _Float16* __restrict__ Wa2,
    const float* __restrict__ ba, const float* __restrict__ skipv,
    const float* __restrict__ ln_g, const float* __restrict__ ln_b,
    const _Float16* __restrict__ xs_cur, _Float16* __restrict__ xs_next,
    float* __restrict__ xout, int l) {
    __shared__ float smem[64 * 130];  // f32 view: row stride 130; f16 view: stride 132
    _Float16* smem_h = (_Float16*)smem;
    int t = blockIdx.y;
    int tid = threadIdx.x;
    int wid = tid >> 6, lane = tid & 63;
    int quad = lane >> 4, ln = lane & 15;
    int node0 = blockIdx.x * 64;
    int nloc = wid * 16 + ln;
    int node = node0 + nloc;
    int arow = min(node, NN - 1);
    const _Float16* grow = outg + ((size_t)t * NN + arow) * CC;
    half8 bf[4];
#pragma unroll
    for (int kt = 0; kt < 4; kt++) {
        uint4 gd = *(const uint4*)(grow + kt * 32 + quad * 8);
        half2t h0 = __builtin_bit_cast(half2t, gd.x), h1 = __builtin_bit_cast(half2t, gd.y);
        half2t h2 = __builtin_bit_cast(half2t, gd.z), h3 = __builtin_bit_cast(half2t, gd.w);
        uint4 pk;
        pk.x = pk2h(gelu_f((float)h0.x), gelu_f((float)h0.y));
        pk.y = pk2h(gelu_f((float)h1.x), gelu_f((float)h1.y));
        pk.z = pk2h(gelu_f((float)h2.x), gelu_f((float)h2.y));
        pk.w = pk2h(gelu_f((float)h3.x), gelu_f((float)h3.y));
        bf[kt] = __builtin_bit_cast(half8, pk);
    }
    const _Float16* Wt = Wa2 + (size_t)(l * 2 + t) * 8 * 2048;
    floatx4 acc[8];
#pragma unroll
    for (int nt = 0; nt < 8; nt++) acc[nt] = (floatx4){0.f, 0.f, 0.f, 0.f};
#pragma unroll
    for (int nt = 0; nt < 8; nt++) {
#pragma unroll
        for (int kt = 0; kt < 4; kt++) {
            half8 af = *(const half8*)(Wt + ((size_t)nt * 4 + kt) * 512 + lane * 8);
            acc[nt] = __builtin_amdgcn_mfma_f32_16x16x32_f16(af, bf[kt], acc[nt], 0, 0, 0);
        }
    }
    float sv = skipv[l * TT + t];
    float beta = 1.f / (1.f + __expf(-sv));
    const _Float16* xt = xs_cur + (size_t)t * NT16R * 2048;
    int tileR = arow >> 4, lnR = arow & 15;
    float xn[8][4];
    float s1 = 0.f, s2 = 0.f;
#pragma unroll
    for (int nt = 0; nt < 8; nt++) {
        int c0 = nt * 16 + quad * 4;
        float4 b4 = *(const float4*)(ba + (l * TT + t) * CC + c0);
        // residual from swizzled x: [tile][kt][quad][ln][8]
        uint2 xw = *(const uint2*)(xt + ((size_t)tileR * 4 + (c0 >> 5)) * 512 +
                                   (((c0 >> 3) & 3) * 16 + lnR) * 8 + (c0 & 7));
        half2t x0 = __builtin_bit_cast(half2t, xw.x), x1 = __builtin_bit_cast(half2t, xw.y);
        float xv[4] = {(float)x0.x, (float)x0.y, (float)x1.x, (float)x1.y};
        float bb[4] = {b4.x, b4.y, b4.z, b4.w};
#pragma unroll
        for (int reg = 0; reg < 4; reg++) {
            float o = acc[nt][reg] + bb[reg];
            float v = beta * o + (1.f - beta) * xv[reg];
            xn[nt][reg] = v;
            s1 += v;
            s2 += v * v;
        }
    }
    s1 += __shfl_xor(s1, 16); s1 += __shfl_xor(s1, 32);
    s2 += __shfl_xor(s2, 16); s2 += __shfl_xor(s2, 32);
    float mu = s1 * (1.f / CC);
    float var = s2 * (1.f / CC) - mu * mu;
    float rs = rsqrtf(var + 1e-5f);
#pragma unroll
    for (int nt = 0; nt < 8; nt++) {
        int c0 = nt * 16 + quad * 4;
        float4 g4 = *(const float4*)(ln_g + (l * TT + t) * CC + c0);
        float4 be4 = *(const float4*)(ln_b + (l * TT + t) * CC + c0);
        float y0 = fmaxf((xn[nt][0] - mu) * rs * g4.x + be4.x, 0.f);
        float y1 = fmaxf((xn[nt][1] - mu) * rs * g4.y + be4.y, 0.f);
        float y2 = fmaxf((xn[nt][2] - mu) * rs * g4.z + be4.z, 0.f);
        float y3 = fmaxf((xn[nt][3] - mu) * rs * g4.w + be4.w, 0.f);
        if (xout) {
            float4 o4 = {y0, y1, y2, y3};
            *(float4*)(smem + nloc * 130 + c0) = o4;
        } else {
            uint2 o;
            o.x = pk2h(y0, y1);
            o.y = pk2h(y2, y3);
            *(uint2*)(smem_h + nloc * 132 + c0) = o;
        }
    }
    __syncthreads();
    if (xout) {
#pragma unroll
        for (int p = 0; p < 8; p++) {
            int c = p * 256 + tid;
            int row = c >> 5, ch = c & 31;
            int nd = node0 + row;
            if (nd < NN)
                *(uint4*)(xout + (size_t)nd * CC + ch * 4) =
                    *(const uint4*)(smem + row * 130 + ch * 4);
        }
    } else {
        // swizzled coalesced copy-out: [tile][kt][lane][8], incl. pad tiles
        _Float16* xnt = xs_next + (size_t)t * NT16R * 2048;
#pragma unroll
        for (int p = 0; p < 4; p++) {
            int c = p * 256 + tid;
            int tl = c >> 8, kt2 = (c >> 6) & 3, l2 = c & 63;
            int q2 = l2 >> 4, ln2 = l2 & 15;
            *(uint4*)(xnt + ((size_t)(blockIdx.x * 4 + tl) * 4 + kt2) * 512 + l2 * 8) =
                *(const uint4*)(smem_h + (tl * 16 + ln2) * 132 + kt2 * 32 + q2 * 8);
        }
    }
}

extern "C" void kernel_launch(void* const* d_in, const int* in_sizes, int n_in,
                              void* d_out, int out_size, void* d_ws, size_t ws_size,
                              hipStream_t stream) {
    const float* x = (const float*)d_in[0];
    const int* ei = (const int*)d_in[1];
    const float* Wk = (const float*)d_in[2];
    const float* bk = (const float*)d_in[3];
    const float* Wq = (const float*)d_in[4];
    const float* bq = (const float*)d_in[5];
    const float* Wv = (const float*)d_in[6];
    const float* bv = (const float*)d_in[7];
    const float* Wa = (const float*)d_in[8];
    const float* ba = (const float*)d_in[9];
    const float* skip = (const float*)d_in[10];
    const float* a_rel = (const float*)d_in[11];
    const float* m_rel = (const float*)d_in[12];
    const float* p_rel = (const float*)d_in[13];
    const float* ln_g = (const float*)d_in[14];
    const float* ln_b = (const float*)d_in[15];

    char* ws = (char*)d_ws;
    size_t off = 0;
    auto alloc = [&](size_t b) {
        size_t o = off;
        off = (off + b + 255) & ~(size_t)255;
        return o;
    };
    _Float16* xsA = (_Float16*)(ws + alloc((size_t)TT * NT16R * 2048 * 2));
    _Float16* xsB = (_Float16*)(ws + alloc((size_t)TT * NT16R * 2048 * 2));
    unsigned char* qkv8 = (unsigned char*)(ws + alloc((size_t)TT * NN * 512));
    _Float16* outg = (_Float16*)(ws + alloc((size_t)TT * NN * CC * 2));
    _Float16* W2 = (_Float16*)(ws + alloc((size_t)2 * TT * 24 * 2048 * 2));
    _Float16* Wa2 = (_Float16*)(ws + alloc((size_t)2 * TT * 8 * 2048 * 2));
    float* beff = (float*)(ws + alloc((size_t)2 * TT * 384 * 4));
    int* counts = (int*)(ws + alloc((size_t)2 * NN * 4));
    int* cursor = (int*)(ws + alloc((size_t)2 * NN * 4));
    int* rowptr = (int*)(ws + alloc((size_t)2 * (NN + 1) * 4));
    int* csr = (int*)(ws + alloc((size_t)2 * EE * 4));
    int* flag = (int*)(ws + alloc(256));
    int* bsum = (int*)(ws + alloc((size_t)2 * SCB * 4 + 256));
    (void)ws_size; (void)in_sizes; (void)n_in; (void)out_size;

    k_detect<<<1, 64, 0, stream>>>(ei, flag);
    (void)hipMemsetAsync(counts, 0, (size_t)2 * NN * 4, stream);
    k_count<<<(2 * EE + 255) / 256, 256, 0, stream>>>(ei, flag, counts);
    k_scan1<<<dim3(SCB, 2), 256, 0, stream>>>(counts, rowptr, bsum);
    k_scan2<<<1, 128, 0, stream>>>(bsum, rowptr);
    k_scan3<<<dim3(SCB, 2), 256, 0, stream>>>(rowptr, bsum, cursor);
    k_scatter<<<(2 * EE + 255) / 256, 256, 0, stream>>>(ei, flag, cursor, csr);
    k_cvt<<<dim3(NT16R / 4, 2), 256, 0, stream>>>(x, xsA);
    k_prep<<<dim3((2 * 384 * 128 + 2 * 128 * 128 + 2 * 384 + 255) / 256, 2), 256, 0, stream>>>(
        Wk, Wq, Wv, Wa, bk, bq, bv, a_rel, m_rel, p_rel, W2, Wa2, beff);

    const int GB = (NN + 31) / 32;
    // layer 0: full qkv for both types
    k_gemm_qkv<6, 0><<<dim3(GB, 2), 256, 0, stream>>>(xsA, W2, beff, qkv8, 0, 0);
    k_attn<<<dim3(NN / 4, 2), 256, 0, stream>>>(qkv8, rowptr, csr, outg);
    k_epilogue<<<dim3((NN + 63) / 64, 2), 256, 0, stream>>>(
        outg, Wa2, ba, skip, ln_g, ln_b, xsA, xsB, nullptr, 0);
    // layer 1: only t0 output needed -> t0 needs q cols [0,128), t1 needs k/v cols [128,384)
    k_gemm_qkv<2, 0><<<dim3(GB, 1), 256, 0, stream>>>(xsB, W2, beff, qkv8, 1, 0);
    k_gemm_qkv<4, 128><<<dim3(GB, 1), 256, 0, stream>>>(xsB, W2, beff, qkv8, 1, 1);
    k_attn<<<dim3(NN / 4, 1), 256, 0, stream>>>(qkv8, rowptr, csr, outg);
    k_epilogue<<<dim3((NN + 63) / 64, 1), 256, 0, stream>>>(
        outg, Wa2, ba, skip, ln_g, ln_b, xsB, nullptr, (float*)d_out, 1);
}